// Round 10
// baseline (391.722 us; speedup 1.0000x reference)
//
#include <hip/hip_runtime.h>
#include <math.h>

#define S_TOK 1024
#define DMODEL 1024
#define PDIM 32
#define NHEADS 16
#define DHEAD 64

__device__ __forceinline__ float wave_reduce_sum(float v) {
#pragma unroll
  for (int m = 32; m >= 1; m >>= 1) v += __shfl_xor(v, m, 64);
  return v;
}
__device__ __forceinline__ float wave_reduce_max(float v) {
#pragma unroll
  for (int m = 32; m >= 1; m >>= 1) v = fmaxf(v, __shfl_xor(v, m, 64));
  return v;
}
__device__ __forceinline__ float wave_reduce_min(float v) {
#pragma unroll
  for (int m = 32; m >= 1; m >>= 1) v = fminf(v, __shfl_xor(v, m, 64));
  return v;
}

#define NBINS 4096
#define CAND_MAX 512

// ---------------- r-GEMM: R[s, n] = ||n||^2 - 2 * p_s . n ----------------
__global__ __launch_bounds__(256) void rgemm_kernel(
    const float* __restrict__ pos, const float* __restrict__ npos,
    float* __restrict__ R, int s0, int N) {
  __shared__ float sAT[32][68];
  __shared__ float sBT[32][2][68];
  __shared__ float s_nrm[128];
  const int tid = threadIdx.x;
  const int n0 = blockIdx.x * 128;
  const int t0 = blockIdx.y * 64;

  {
    const float4* g = reinterpret_cast<const float4*>(pos + (size_t)(s0 + t0) * PDIM);
#pragma unroll
    for (int i = 0; i < 2; ++i) {
      int f = tid + i * 256;
      float4 v = g[f];
      int t = f >> 3, ks = (f & 7) * 4;
      sAT[ks + 0][t] = v.x; sAT[ks + 1][t] = v.y;
      sAT[ks + 2][t] = v.z; sAT[ks + 3][t] = v.w;
    }
    const float4* gb = reinterpret_cast<const float4*>(npos + (size_t)n0 * PDIM);
#pragma unroll
    for (int i = 0; i < 4; ++i) {
      int f = tid + i * 256;
      float4 v = gb[f];
      int n = f >> 3, ks = (f & 7) * 4;
      int hh = n >> 6, m = n & 63;
      sBT[ks + 0][hh][m] = v.x; sBT[ks + 1][hh][m] = v.y;
      sBT[ks + 2][hh][m] = v.z; sBT[ks + 3][hh][m] = v.w;
    }
  }
  __syncthreads();
  if (tid < 128) {
    int hh = tid >> 6, m = tid & 63;
    float acc = 0.f;
#pragma unroll
    for (int k = 0; k < 32; ++k) { float b = sBT[k][hh][m]; acc += b * b; }
    s_nrm[tid] = acc;
  }
  __syncthreads();

  const int tt = tid >> 4, nn = tid & 15;
  float acc[4][8];
#pragma unroll
  for (int i = 0; i < 4; ++i)
#pragma unroll
    for (int j = 0; j < 8; ++j) acc[i][j] = 0.f;

#pragma unroll 8
  for (int k = 0; k < 32; ++k) {
    const float4 a = *reinterpret_cast<const float4*>(&sAT[k][tt * 4]);
    const float4 b0 = *reinterpret_cast<const float4*>(&sBT[k][0][nn * 4]);
    const float4 b1 = *reinterpret_cast<const float4*>(&sBT[k][1][nn * 4]);
    const float av[4] = {a.x, a.y, a.z, a.w};
#pragma unroll
    for (int t = 0; t < 4; ++t) {
      acc[t][0] += av[t] * b0.x; acc[t][1] += av[t] * b0.y;
      acc[t][2] += av[t] * b0.z; acc[t][3] += av[t] * b0.w;
      acc[t][4] += av[t] * b1.x; acc[t][5] += av[t] * b1.y;
      acc[t][6] += av[t] * b1.z; acc[t][7] += av[t] * b1.w;
    }
  }

  const float n00 = s_nrm[nn * 4 + 0], n01 = s_nrm[nn * 4 + 1];
  const float n02 = s_nrm[nn * 4 + 2], n03 = s_nrm[nn * 4 + 3];
  const float n10 = s_nrm[64 + nn * 4 + 0], n11 = s_nrm[64 + nn * 4 + 1];
  const float n12 = s_nrm[64 + nn * 4 + 2], n13 = s_nrm[64 + nn * 4 + 3];
#pragma unroll
  for (int t = 0; t < 4; ++t) {
    const size_t ro = (size_t)(t0 + tt * 4 + t) * N + n0;
    float4 r0 = make_float4(fmaf(-2.f, acc[t][0], n00), fmaf(-2.f, acc[t][1], n01),
                            fmaf(-2.f, acc[t][2], n02), fmaf(-2.f, acc[t][3], n03));
    float4 r1 = make_float4(fmaf(-2.f, acc[t][4], n10), fmaf(-2.f, acc[t][5], n11),
                            fmaf(-2.f, acc[t][6], n12), fmaf(-2.f, acc[t][7], n13));
    *reinterpret_cast<float4*>(R + ro + nn * 4) = r0;
    *reinterpret_cast<float4*>(R + ro + 64 + nn * 4) = r1;
  }
}

// ---------------- slim select on precomputed R row ----------------
template <int N, int K>
__global__ __launch_bounds__(256) void select2_kernel(
    const float* __restrict__ R, const float* __restrict__ pos,
    const float* __restrict__ npos, int s0,
    int* __restrict__ out_idx, float* __restrict__ out_dist) {
  const int bid = blockIdx.x;
  const int s = s0 + bid;
  const int tid = threadIdx.x;
  const int lane = tid & 63;
  const int wave = tid >> 6;

  __shared__ float s_dist[N];
  __shared__ unsigned s_hist[NBINS];
  __shared__ unsigned s_part[256];
  __shared__ float4 s_p4[8];
  __shared__ float s_red[16];
  __shared__ float s_lo, s_scale;
  __shared__ int s_B, s_need, s_cnt, s_ccnt;
  __shared__ int s_selidx[K];
  __shared__ float s_seldist[K];
  __shared__ int s_cidx[CAND_MAX];
  __shared__ float s_cdist[CAND_MAX];

  if (tid < 8) s_p4[tid] = reinterpret_cast<const float4*>(pos + (size_t)s * PDIM)[tid];
  for (int j = tid; j < K; j += 256) s_selidx[j] = 0;
  for (int b = tid; b < NBINS; b += 256) s_hist[b] = 0u;
  __syncthreads();

  float lmin = 3.0e38f, lmax = -3.0e38f;
  const float* row = R + (size_t)bid * N;
#pragma unroll 4
  for (int i = 0; i < N / 256; ++i) {
    float v = row[tid + i * 256];
    s_dist[tid + i * 256] = v;
    lmin = fminf(lmin, v);
    lmax = fmaxf(lmax, v);
  }
  lmin = wave_reduce_min(lmin);
  lmax = wave_reduce_max(lmax);
  if (lane == 0) { s_red[wave] = lmin; s_red[8 + wave] = lmax; }
  __syncthreads();
  if (tid == 0) {
    float lo = s_red[0], hi = s_red[8];
    for (int w2 = 1; w2 < 4; ++w2) {
      lo = fminf(lo, s_red[w2]);
      hi = fmaxf(hi, s_red[8 + w2]);
    }
    s_lo = lo;
    s_scale = (float)NBINS / fmaxf(hi - lo, 1e-30f);
  }
  __syncthreads();

  const float lo = s_lo, scale = s_scale;
  for (int n = tid; n < N; n += 256) {
    int b = min(NBINS - 1, (int)((s_dist[n] - lo) * scale));
    atomicAdd(&s_hist[b], 1u);
  }
  __syncthreads();

  unsigned psum = 0;
#pragma unroll 4
  for (int b = tid * 16; b < tid * 16 + 16; ++b) psum += s_hist[b];
  s_part[tid] = psum;
  __syncthreads();
  if (tid == 0) {
    unsigned cum = 0;
    int c = 0;
    for (; c < 256; ++c) {
      unsigned pc = s_part[c];
      if (cum + pc >= (unsigned)K) break;
      cum += pc;
    }
    int b = c * 16;
    for (;; ++b) {
      unsigned cb = s_hist[b];
      if (cum + cb >= (unsigned)K) break;
      cum += cb;
    }
    s_B = b;
    s_need = K - (int)cum;
    s_cnt = 0;
    s_ccnt = 0;
  }
  __syncthreads();

  const int B = s_B;
  for (int n = tid; n < N; n += 256) {
    float d = s_dist[n];
    int b = min(NBINS - 1, (int)((d - lo) * scale));
    if (b < B) {
      int p = atomicAdd(&s_cnt, 1);
      s_selidx[p] = n;
    } else if (b == B) {
      int e = atomicAdd(&s_ccnt, 1);
      if (e < CAND_MAX) { s_cidx[e] = n; s_cdist[e] = d; }
    }
  }
  __syncthreads();

  const int M = s_ccnt < CAND_MAX ? s_ccnt : CAND_MAX;
  const int need = s_need;
  const int base = s_cnt;
  for (int i = tid; i < M; i += 256) {
    float di = s_cdist[i];
    int idxi = s_cidx[i];
    int rank = 0;
    for (int j = 0; j < M; ++j) {
      float dj = s_cdist[j];
      rank += (dj < di || (dj == di && s_cidx[j] < idxi)) ? 1 : 0;
    }
    if (rank < need) s_selidx[base + rank] = idxi;
  }
  __syncthreads();

  {
    const int g = tid >> 3, sl = tid & 7;
    const float4 pv = s_p4[sl];
    for (int j = g; j < K; j += 32) {
      const float4 nv =
          *reinterpret_cast<const float4*>(npos + (size_t)s_selidx[j] * PDIM + sl * 4);
      float dx = pv.x - nv.x, dy = pv.y - nv.y, dz = pv.z - nv.z, dw = pv.w - nv.w;
      float d = dx * dx + dy * dy + dz * dz + dw * dw;
      d += __shfl_xor(d, 1, 64);
      d += __shfl_xor(d, 2, 64);
      d += __shfl_xor(d, 4, 64);
      if (sl == 0) s_seldist[j] = d;
    }
  }
  __syncthreads();
  for (int j = tid; j < K; j += 256) {
    out_idx[(size_t)s * K + j] = s_selidx[j];
    out_dist[(size_t)s * K + j] = s_seldist[j];
  }
}

// ---------------- fallback: fused distance+select ----------------
template <int N, int K>
__global__ __launch_bounds__(256) void select_topk_fused_kernel(
    const float* __restrict__ pos, const float* __restrict__ npos,
    int* __restrict__ out_idx, float* __restrict__ out_dist) {
  const int s = blockIdx.x;
  const int tid = threadIdx.x;
  const int lane = tid & 63;
  const int wave = tid >> 6;
  const int sl = lane & 7;
  const int rw = lane >> 3;

  __shared__ float s_dist[N];
  __shared__ unsigned s_hist[NBINS];
  __shared__ unsigned s_part[256];
  __shared__ float4 s_p4[8];
  __shared__ float s_red[16];
  __shared__ float s_lo, s_scale;
  __shared__ int s_B, s_need;
  __shared__ int s_cnt, s_ccnt;
  __shared__ int s_selidx[K];
  __shared__ float s_seldist[K];
  __shared__ int s_cidx[CAND_MAX];
  __shared__ float s_cdist[CAND_MAX];

  if (tid < 8) s_p4[tid] = reinterpret_cast<const float4*>(pos + (size_t)s * PDIM)[tid];
  for (int j = tid; j < K; j += 256) { s_selidx[j] = 0; s_seldist[j] = 0.f; }
  for (int b = tid; b < NBINS; b += 256) s_hist[b] = 0u;
  __syncthreads();

  const float4 pv = s_p4[sl];
  float lmin = 3.0e38f, lmax = -3.0e38f;
  const int rows_per_wave = N / 4;
  const int rbase = wave * rows_per_wave;
  for (int it = 0; it < rows_per_wave; it += 16) {
    const int ra = rbase + it + rw;
    const int rb = ra + 8;
    const float4 na = *reinterpret_cast<const float4*>(npos + (size_t)ra * PDIM + sl * 4);
    const float4 nb = *reinterpret_cast<const float4*>(npos + (size_t)rb * PDIM + sl * 4);
    float dax = pv.x - na.x, day = pv.y - na.y, daz = pv.z - na.z, daw = pv.w - na.w;
    float dbx = pv.x - nb.x, dby = pv.y - nb.y, dbz = pv.z - nb.z, dbw = pv.w - nb.w;
    float da = dax * dax + day * day + daz * daz + daw * daw;
    float db = dbx * dbx + dby * dby + dbz * dbz + dbw * dbw;
    da += __shfl_xor(da, 1, 64); da += __shfl_xor(da, 2, 64); da += __shfl_xor(da, 4, 64);
    db += __shfl_xor(db, 1, 64); db += __shfl_xor(db, 2, 64); db += __shfl_xor(db, 4, 64);
    lmin = fminf(lmin, fminf(da, db));
    lmax = fmaxf(lmax, fmaxf(da, db));
    if (sl == 0) { s_dist[ra] = da; s_dist[rb] = db; }
  }
  lmin = wave_reduce_min(lmin);
  lmax = wave_reduce_max(lmax);
  if (lane == 0) { s_red[wave] = lmin; s_red[8 + wave] = lmax; }
  __syncthreads();
  if (tid == 0) {
    float lo = s_red[0], hi = s_red[8];
    for (int w2 = 1; w2 < 4; ++w2) {
      lo = fminf(lo, s_red[w2]);
      hi = fmaxf(hi, s_red[8 + w2]);
    }
    s_lo = lo;
    s_scale = (float)NBINS / fmaxf(hi - lo, 1e-30f);
  }
  __syncthreads();

  const float lo = s_lo, scale = s_scale;
  for (int n = tid; n < N; n += 256) {
    int b = min(NBINS - 1, (int)((s_dist[n] - lo) * scale));
    atomicAdd(&s_hist[b], 1u);
  }
  __syncthreads();

  unsigned psum = 0;
#pragma unroll 4
  for (int b = tid * 16; b < tid * 16 + 16; ++b) psum += s_hist[b];
  s_part[tid] = psum;
  __syncthreads();
  if (tid == 0) {
    unsigned cum = 0;
    int c = 0;
    for (; c < 256; ++c) {
      unsigned pc = s_part[c];
      if (cum + pc >= (unsigned)K) break;
      cum += pc;
    }
    int b = c * 16;
    for (;; ++b) {
      unsigned cb = s_hist[b];
      if (cum + cb >= (unsigned)K) break;
      cum += cb;
    }
    s_B = b;
    s_need = K - (int)cum;
    s_cnt = 0;
    s_ccnt = 0;
  }
  __syncthreads();

  const int B = s_B;
  for (int n = tid; n < N; n += 256) {
    float d = s_dist[n];
    int b = min(NBINS - 1, (int)((d - lo) * scale));
    if (b < B) {
      int p = atomicAdd(&s_cnt, 1);
      s_selidx[p] = n;
      s_seldist[p] = d;
    } else if (b == B) {
      int e = atomicAdd(&s_ccnt, 1);
      if (e < CAND_MAX) { s_cidx[e] = n; s_cdist[e] = d; }
    }
  }
  __syncthreads();

  const int M = s_ccnt < CAND_MAX ? s_ccnt : CAND_MAX;
  const int need = s_need;
  const int base = s_cnt;
  for (int i = tid; i < M; i += 256) {
    unsigned ki = __float_as_uint(s_cdist[i]);
    int idxi = s_cidx[i];
    int rank = 0;
    for (int j = 0; j < M; ++j) {
      unsigned kj = __float_as_uint(s_cdist[j]);
      rank += (kj < ki || (kj == ki && s_cidx[j] < idxi)) ? 1 : 0;
    }
    if (rank < need) {
      s_selidx[base + rank] = idxi;
      s_seldist[base + rank] = s_cdist[i];
    }
  }
  __syncthreads();

  for (int j = tid; j < K; j += 256) {
    out_idx[(size_t)s * K + j] = s_selidx[j];
    out_dist[(size_t)s * K + j] = s_seldist[j];
  }
}

// ---------------- attn token kernel (pass-2 over gate survivors only) ----------------
__global__ __launch_bounds__(256) void attn_token_kernel(
    const float* __restrict__ x,
    const float* __restrict__ tau_q, const float* __restrict__ tau_k,
    const float* __restrict__ tau_v,
    const float* __restrict__ qk_neurons, const float* __restrict__ v_neurons,
    const int* __restrict__ idx_qk, const float* __restrict__ d_qk,
    const int* __restrict__ idx_v, const float* __restrict__ d_v,
    float* __restrict__ Qh, float* __restrict__ Kh, float* __restrict__ Vh,
    float* __restrict__ loss_acc) {
  const int s = blockIdx.x;
  const int tid = threadIdx.x;
  const int lane = tid & 63;
  const int wave = tid >> 6;
  __shared__ __align__(16) float s_x[DMODEL];
  __shared__ float s_act_qk[64], s_act_v[64];
  __shared__ float s_wq[64], s_wk[64], s_wv[64];
  __shared__ float s_gq[64], s_gv[64];
  __shared__ int s_iqk[64], s_iv[64];
  __shared__ int s_qklist[64], s_vlist[64];
  __shared__ int s_qkcnt, s_vcnt;

  for (int i = tid; i < DMODEL; i += 256) s_x[i] = x[(size_t)s * DMODEL + i];
  if (tid < 64) {
    s_iqk[tid] = idx_qk[s * 64 + tid];
    s_iv[tid] = idx_v[s * 64 + tid];
  }
  __syncthreads();

  const float4* x4 = reinterpret_cast<const float4*>(s_x);
  for (int c = wave * 16; c < wave * 16 + 16; ++c) {
    const float4* row4 = reinterpret_cast<const float4*>(qk_neurons + (size_t)s_iqk[c] * DMODEL);
    float acc = 0.f;
#pragma unroll
    for (int k = 0; k < 4; ++k) {
      float4 rv = row4[lane + k * 64];
      float4 xv = x4[lane + k * 64];
      acc += rv.x * xv.x + rv.y * xv.y + rv.z * xv.z + rv.w * xv.w;
    }
    acc = wave_reduce_sum(acc);
    if (lane == 0) s_act_qk[c] = acc;
  }
  for (int c = wave * 16; c < wave * 16 + 16; ++c) {
    const float4* row4 = reinterpret_cast<const float4*>(v_neurons + (size_t)s_iv[c] * DMODEL);
    float acc = 0.f;
#pragma unroll
    for (int k = 0; k < 4; ++k) {
      float4 rv = row4[lane + k * 64];
      float4 xv = x4[lane + k * 64];
      acc += rv.x * xv.x + rv.y * xv.y + rv.z * xv.z + rv.w * xv.w;
    }
    acc = wave_reduce_sum(acc);
    if (lane == 0) s_act_v[c] = acc;
  }
  __syncthreads();

  if (wave < 3) {
    const float a = (wave == 2) ? s_act_v[lane] : s_act_qk[lane];
    const float tau = (wave == 0) ? tau_q[s] : (wave == 1) ? tau_k[s] : tau_v[s];
    float raw = a - tau;
    float gate = (raw > 0.f) ? raw : 1e-8f * __expf(raw);
    float eg = __expf(gate) - 1.f;
    int rank = 0;
    for (int j = 0; j < 64; ++j) {
      float vj = __shfl(eg, j, 64);
      rank += ((vj > eg) || (vj == eg && j < lane)) ? 1 : 0;
    }
    unsigned long long bm = __ballot(rank == 31);
    int srcl = __ffsll(bm) - 1;
    float kthv = __shfl(eg, srcl, 64);
    float w = (eg >= kthv) ? eg : 0.f;
    float gsum = wave_reduce_sum(w) + 1e-8f;
    float strength = tanhf(wave_reduce_max(eg));
    float g = w / gsum * strength;
    if (wave == 0) { s_wq[lane] = a * g; s_gq[lane] = g; }
    else if (wave == 1) { s_wk[lane] = a * g; }
    else { s_wv[lane] = a * g; s_gv[lane] = g; }
  }
  __syncthreads();

  // survivor compaction (deterministic, index-ordered)
  if (wave == 0) {
    bool pred = (s_wq[lane] != 0.f) || (s_wk[lane] != 0.f);
    unsigned long long m = __ballot(pred);
    int pos = __popcll(m & ((1ull << lane) - 1ull));
    if (pred) s_qklist[pos] = lane;
    if (lane == 0) s_qkcnt = __popcll(m);
  } else if (wave == 1) {
    bool pred = (s_wv[lane] != 0.f);
    unsigned long long m = __ballot(pred);
    int pos = __popcll(m & ((1ull << lane) - 1ull));
    if (pred) s_vlist[pos] = lane;
    if (lane == 0) s_vcnt = __popcll(m);
  } else if (wave == 2) {
    float pl = s_gq[lane] * d_qk[s * 64 + lane] + s_gv[lane] * d_v[s * 64 + lane];
    pl = wave_reduce_sum(pl);
    if (lane == 0) atomicAdd(loss_acc, pl * (1.f / 65536.f));
  }
  __syncthreads();

  // pass 2 over survivors only (skipped rows have exactly-zero weight)
  const int d0 = tid * 4;
  const int nqk = s_qkcnt, nv = s_vcnt;
  float aq0 = 0, aq1 = 0, aq2 = 0, aq3 = 0;
  float ak0 = 0, ak1 = 0, ak2 = 0, ak3 = 0;
  float av0 = 0, av1 = 0, av2 = 0, av3 = 0;
  for (int j = 0; j < nqk; ++j) {
    const int c = s_qklist[j];
    const float4 r = *reinterpret_cast<const float4*>(qk_neurons + (size_t)s_iqk[c] * DMODEL + d0);
    const float wq = s_wq[c], wk = s_wk[c];
    aq0 += wq * r.x; aq1 += wq * r.y; aq2 += wq * r.z; aq3 += wq * r.w;
    ak0 += wk * r.x; ak1 += wk * r.y; ak2 += wk * r.z; ak3 += wk * r.w;
  }
  for (int j = 0; j < nv; ++j) {
    const int c = s_vlist[j];
    const float4 r = *reinterpret_cast<const float4*>(v_neurons + (size_t)s_iv[c] * DMODEL + d0);
    const float wv = s_wv[c];
    av0 += wv * r.x; av1 += wv * r.y; av2 += wv * r.z; av3 += wv * r.w;
  }
  const int hh = d0 >> 6;
  const int dh = d0 & 63;
  const size_t base = ((size_t)hh * S_TOK + s) * DHEAD + dh;
  *reinterpret_cast<float4*>(Qh + base) = make_float4(aq0, aq1, aq2, aq3);
  *reinterpret_cast<float4*>(Kh + base) = make_float4(ak0, ak1, ak2, ak3);
  *reinterpret_cast<float4*>(Vh + base) = make_float4(av0, av1, av2, av3);
}

// ---------------- split-K attention: partial kernel (QBLK=32, P kept in registers) ----------
// block -> (h, qt, chunk of 256 keys); slot: o[32][64], m[32], l[32] = 2112 floats.
// PV gets cross-key P via intra-wave shuffles (16-lane qp-group is wave-contained) -> no sP,
// 2 barriers/tile instead of 3, LDS 43.5 KB -> 3 blocks/CU.
__global__ __launch_bounds__(256) void attention_partial_kernel(
    const float* __restrict__ Q, const float* __restrict__ K,
    const float* __restrict__ V, float* __restrict__ part) {
  __shared__ float sQ[32][68];
  __shared__ float sKT[64][68];
  __shared__ float sV[64][68];

  const int tid = threadIdx.x;
  const int bid = blockIdx.x;
  const int sw = (bid & 7) * 160 + (bid >> 3);  // XCD-contiguous
  const int h = sw / 80;
  const int r80 = sw % 80;
  int qt, c;
  if (r80 < 8) { qt = r80; c = 0; }
  else if (r80 < 24) { qt = 8 + ((r80 - 8) >> 1); c = (r80 - 8) & 1; }
  else if (r80 < 48) { qt = 16 + (r80 - 24) / 3; c = (r80 - 24) % 3; }
  else { qt = 24 + ((r80 - 48) >> 2); c = (r80 - 48) & 3; }
  const int q0 = qt * 32;
  const int kstart = c * 256;
  const int kend = min((qt + 1) * 32, kstart + 256);
  const int ntiles = (kend - kstart + 63) >> 6;
  const int g = qt >> 3;
  const int sbase = qt + 4 * g * (g - 1) + (qt - 8 * g) * g;
  float* slot = part + ((size_t)h * 80 + sbase + c) * 2112;

  const int qp = tid >> 4;
  const int kg = tid & 15;
  const int lane = tid & 63;
  const int shbase = lane & 48;  // first lane of this qp-group within the wave

  const float* Qb = Q + (size_t)h * S_TOK * DHEAD;
  const float* Kb = K + (size_t)h * S_TOK * DHEAD;
  const float* Vb = V + (size_t)h * S_TOK * DHEAD;

  {
    const float4* Qg4 = reinterpret_cast<const float4*>(Qb + (size_t)q0 * DHEAD);
    for (int f = tid; f < 512; f += 256) {
      float4 v = Qg4[f];
      int row = f >> 4, c4 = f & 15;
      float* dst = &sQ[row][c4 * 4];
      dst[0] = v.x * 0.125f; dst[1] = v.y * 0.125f;
      dst[2] = v.z * 0.125f; dst[3] = v.w * 0.125f;
    }
  }

  float m0 = -3.0e38f, m1 = -3.0e38f, l0 = 0.f, l1 = 0.f;
  float4 o0 = make_float4(0.f, 0.f, 0.f, 0.f);
  float4 o1 = make_float4(0.f, 0.f, 0.f, 0.f);

  const int qg0 = q0 + 2 * qp, qg1 = qg0 + 1;

  for (int t = 0; t < ntiles; ++t) {
    const int k0 = kstart + t * 64;
    __syncthreads();  // previous-iter readers done (also covers Q staging at t=0)
    {
      const float4* Kg4 = reinterpret_cast<const float4*>(Kb + (size_t)k0 * DHEAD);
      for (int it = 0; it < 4; ++it) {
        int f = tid + it * 256;
        int row = f & 63;
        int c4 = f >> 6;
        float4 v = Kg4[row * 16 + c4];
        sKT[c4 * 4 + 0][row] = v.x; sKT[c4 * 4 + 1][row] = v.y;
        sKT[c4 * 4 + 2][row] = v.z; sKT[c4 * 4 + 3][row] = v.w;
      }
      const float4* Vg4 = reinterpret_cast<const float4*>(Vb + (size_t)k0 * DHEAD);
      for (int it = 0; it < 4; ++it) {
        int f = tid + it * 256;
        int row = f >> 4, c4 = f & 15;
        *reinterpret_cast<float4*>(&sV[row][c4 * 4]) = Vg4[f];
      }
    }
    __syncthreads();

    // ---- scores: rows {2qp, 2qp+1} x keys {4kg..4kg+3} ----
    float s00 = 0, s01 = 0, s02 = 0, s03 = 0;
    float s10 = 0, s11 = 0, s12 = 0, s13 = 0;
#pragma unroll
    for (int d4 = 0; d4 < 16; ++d4) {
      float4 qv0 = *reinterpret_cast<const float4*>(&sQ[2 * qp + 0][d4 * 4]);
      float4 qv1 = *reinterpret_cast<const float4*>(&sQ[2 * qp + 1][d4 * 4]);
#pragma unroll
      for (int e = 0; e < 4; ++e) {
        float4 kv = *reinterpret_cast<const float4*>(&sKT[d4 * 4 + e][kg * 4]);
        float qa = (e == 0) ? qv0.x : (e == 1) ? qv0.y : (e == 2) ? qv0.z : qv0.w;
        float qb = (e == 0) ? qv1.x : (e == 1) ? qv1.y : (e == 2) ? qv1.z : qv1.w;
        s00 += qa * kv.x; s01 += qa * kv.y; s02 += qa * kv.z; s03 += qa * kv.w;
        s10 += qb * kv.x; s11 += qb * kv.y; s12 += qb * kv.z; s13 += qb * kv.w;
      }
    }
    // causal mask
    const int kb = k0 + kg * 4;
    if (kb + 0 > qg0) s00 = -3.0e38f;
    if (kb + 1 > qg0) s01 = -3.0e38f;
    if (kb + 2 > qg0) s02 = -3.0e38f;
    if (kb + 3 > qg0) s03 = -3.0e38f;
    if (kb + 0 > qg1) s10 = -3.0e38f;
    if (kb + 1 > qg1) s11 = -3.0e38f;
    if (kb + 2 > qg1) s12 = -3.0e38f;
    if (kb + 3 > qg1) s13 = -3.0e38f;

    // online softmax: row stats across the 16-lane group sharing qp
    float lm0 = fmaxf(fmaxf(s00, s01), fmaxf(s02, s03));
    float lm1 = fmaxf(fmaxf(s10, s11), fmaxf(s12, s13));
#pragma unroll
    for (int mm = 1; mm <= 8; mm <<= 1) {
      lm0 = fmaxf(lm0, __shfl_xor(lm0, mm, 64));
      lm1 = fmaxf(lm1, __shfl_xor(lm1, mm, 64));
    }
    float mn0 = fmaxf(m0, lm0), mn1 = fmaxf(m1, lm1);
    float sc0 = __expf(m0 - mn0), sc1 = __expf(m1 - mn1);
    float p00 = __expf(s00 - mn0), p01 = __expf(s01 - mn0);
    float p02 = __expf(s02 - mn0), p03 = __expf(s03 - mn0);
    float p10 = __expf(s10 - mn1), p11 = __expf(s11 - mn1);
    float p12 = __expf(s12 - mn1), p13 = __expf(s13 - mn1);
    float ls0 = p00 + p01 + p02 + p03;
    float ls1 = p10 + p11 + p12 + p13;
#pragma unroll
    for (int mm = 1; mm <= 8; mm <<= 1) {
      ls0 += __shfl_xor(ls0, mm, 64);
      ls1 += __shfl_xor(ls1, mm, 64);
    }
    l0 = l0 * sc0 + ls0;
    l1 = l1 * sc1 + ls1;
    o0.x *= sc0; o0.y *= sc0; o0.z *= sc0; o0.w *= sc0;
    o1.x *= sc1; o1.y *= sc1; o1.z *= sc1; o1.w *= sc1;
    m0 = mn0; m1 = mn1;

    // ---- PV via in-wave shuffle transpose of P (no LDS, no barrier) ----
#pragma unroll
    for (int k4 = 0; k4 < 16; ++k4) {
      const int sl2 = shbase + k4;
      float w00 = __shfl(p00, sl2, 64), w01 = __shfl(p01, sl2, 64);
      float w02 = __shfl(p02, sl2, 64), w03 = __shfl(p03, sl2, 64);
      float w10 = __shfl(p10, sl2, 64), w11 = __shfl(p11, sl2, 64);
      float w12 = __shfl(p12, sl2, 64), w13 = __shfl(p13, sl2, 64);
#pragma unroll
      for (int e = 0; e < 4; ++e) {
        float4 vv = *reinterpret_cast<const float4*>(&sV[k4 * 4 + e][kg * 4]);
        float w0 = (e == 0) ? w00 : (e == 1) ? w01 : (e == 2) ? w02 : w03;
        float w1 = (e == 0) ? w10 : (e == 1) ? w11 : (e == 2) ? w12 : w13;
        o0.x += w0 * vv.x; o0.y += w0 * vv.y; o0.z += w0 * vv.z; o0.w += w0 * vv.w;
        o1.x += w1 * vv.x; o1.y += w1 * vv.y; o1.z += w1 * vv.z; o1.w += w1 * vv.w;
      }
    }
  }

  *reinterpret_cast<float4*>(slot + (2 * qp + 0) * 64 + kg * 4) = o0;
  *reinterpret_cast<float4*>(slot + (2 * qp + 1) * 64 + kg * 4) = o1;
  if (kg == 0) {
    slot[2048 + 2 * qp + 0] = m0;
    slot[2048 + 2 * qp + 1] = m1;
    slot[2080 + 2 * qp + 0] = l0;
    slot[2080 + 2 * qp + 1] = l1;
  }
}

// ---------------- split-K attention: combine ----------------
__global__ __launch_bounds__(256) void attention_combine_kernel(
    const float* __restrict__ part, float* __restrict__ attn_out) {
  const int bid = blockIdx.x;  // 512 = h*32 + qt
  const int h = bid >> 5, qt = bid & 31;
  const int g = qt >> 3;
  const int sbase = qt + 4 * g * (g - 1) + (qt - 8 * g) * g;
  const int nc = g + 1;
  const float* P0 = part + ((size_t)h * 80 + sbase) * 2112;
  const int tid = threadIdx.x;
  const int r = tid >> 3, dg = tid & 7;

  float mstar = -3.0e38f;
  for (int c2 = 0; c2 < nc; ++c2) mstar = fmaxf(mstar, P0[c2 * 2112 + 2048 + r]);
  float a0 = 0, a1 = 0, a2 = 0, a3 = 0, a4 = 0, a5 = 0, a6 = 0, a7 = 0;
  float lsum = 0.f;
  for (int c2 = 0; c2 < nc; ++c2) {
    const float* S = P0 + c2 * 2112;
    float f = __expf(S[2048 + r] - mstar);
    lsum += S[2080 + r] * f;
    const float4* o4 = reinterpret_cast<const float4*>(S + r * 64 + dg * 8);
    float4 u = o4[0], v = o4[1];
    a0 += u.x * f; a1 += u.y * f; a2 += u.z * f; a3 += u.w * f;
    a4 += v.x * f; a5 += v.y * f; a6 += v.z * f; a7 += v.w * f;
  }
  const float inv = 1.f / lsum;
  float* dst = attn_out + (size_t)(qt * 32 + r) * DMODEL + h * DHEAD + dg * 8;
  *reinterpret_cast<float4*>(dst) = make_float4(a0 * inv, a1 * inv, a2 * inv, a3 * inv);
  *reinterpret_cast<float4*>(dst + 4) = make_float4(a4 * inv, a5 * inv, a6 * inv, a7 * inv);
}

// ---------------- fallback single-pass attention (small ws) ----------------
__global__ __launch_bounds__(256) void attention_kernel(
    const float* __restrict__ Q, const float* __restrict__ K,
    const float* __restrict__ V, float* __restrict__ attn_out) {
  __shared__ float sQ[32][68];
  __shared__ float sKT[64][68];
  __shared__ float sV[64][68];
  __shared__ float sP[32][68];

  const int tid = threadIdx.x;
  const int bid = blockIdx.x;
  const int xcd = bid & 7;
  const int slot = bid >> 3;
  const int h = xcd + 8 * (slot >> 5);
  const int w = slot & 31;
  const int phase = w >> 4;
  const int j0 = w & 15;
  const int qt = phase ? (31 - j0) : j0;
  const int q0 = qt * 32;
  const int ntiles = (qt + 2) >> 1;

  const int qp = tid >> 4;
  const int kg = tid & 15;

  const float* Qb = Q + (size_t)h * S_TOK * DHEAD;
  const float* Kb = K + (size_t)h * S_TOK * DHEAD;
  const float* Vb = V + (size_t)h * S_TOK * DHEAD;

  {
    const float4* Qg4 = reinterpret_cast<const float4*>(Qb + (size_t)q0 * DHEAD);
    for (int f = tid; f < 512; f += 256) {
      float4 v = Qg4[f];
      int row = f >> 4, c4 = f & 15;
      float* dst = &sQ[row][c4 * 4];
      dst[0] = v.x * 0.125f; dst[1] = v.y * 0.125f;
      dst[2] = v.z * 0.125f; dst[3] = v.w * 0.125f;
    }
  }

  float m0 = -3.0e38f, m1 = -3.0e38f, l0 = 0.f, l1 = 0.f;
  float4 o0 = make_float4(0.f, 0.f, 0.f, 0.f);
  float4 o1 = make_float4(0.f, 0.f, 0.f, 0.f);

  const int qg0 = q0 + 2 * qp, qg1 = qg0 + 1;

  for (int t = 0; t < ntiles; ++t) {
    const int k0 = t * 64;
    __syncthreads();
    {
      const float4* Kg4 = reinterpret_cast<const float4*>(Kb + (size_t)k0 * DHEAD);
      for (int it = 0; it < 4; ++it) {
        int f = tid + it * 256;
        int row = f & 63;
        int c4 = f >> 6;
        float4 v = Kg4[row * 16 + c4];
        sKT[c4 * 4 + 0][row] = v.x; sKT[c4 * 4 + 1][row] = v.y;
        sKT[c4 * 4 + 2][row] = v.z; sKT[c4 * 4 + 3][row] = v.w;
      }
      const float4* Vg4 = reinterpret_cast<const float4*>(Vb + (size_t)k0 * DHEAD);
      for (int it = 0; it < 4; ++it) {
        int f = tid + it * 256;
        int row = f >> 4, c4 = f & 15;
        *reinterpret_cast<float4*>(&sV[row][c4 * 4]) = Vg4[f];
      }
    }
    __syncthreads();

    float s00 = 0, s01 = 0, s02 = 0, s03 = 0;
    float s10 = 0, s11 = 0, s12 = 0, s13 = 0;
#pragma unroll
    for (int d4 = 0; d4 < 16; ++d4) {
      float4 qv0 = *reinterpret_cast<const float4*>(&sQ[2 * qp + 0][d4 * 4]);
      float4 qv1 = *reinterpret_cast<const float4*>(&sQ[2 * qp + 1][d4 * 4]);
#pragma unroll
      for (int e = 0; e < 4; ++e) {
        float4 kv = *reinterpret_cast<const float4*>(&sKT[d4 * 4 + e][kg * 4]);
        float qa = (e == 0) ? qv0.x : (e == 1) ? qv0.y : (e == 2) ? qv0.z : qv0.w;
        float qb = (e == 0) ? qv1.x : (e == 1) ? qv1.y : (e == 2) ? qv1.z : qv1.w;
        s00 += qa * kv.x; s01 += qa * kv.y; s02 += qa * kv.z; s03 += qa * kv.w;
        s10 += qb * kv.x; s11 += qb * kv.y; s12 += qb * kv.z; s13 += qb * kv.w;
      }
    }
    const int kb = k0 + kg * 4;
    if (kb + 0 > qg0) s00 = -3.0e38f;
    if (kb + 1 > qg0) s01 = -3.0e38f;
    if (kb + 2 > qg0) s02 = -3.0e38f;
    if (kb + 3 > qg0) s03 = -3.0e38f;
    if (kb + 0 > qg1) s10 = -3.0e38f;
    if (kb + 1 > qg1) s11 = -3.0e38f;
    if (kb + 2 > qg1) s12 = -3.0e38f;
    if (kb + 3 > qg1) s13 = -3.0e38f;

    float lm0 = fmaxf(fmaxf(s00, s01), fmaxf(s02, s03));
    float lm1 = fmaxf(fmaxf(s10, s11), fmaxf(s12, s13));
#pragma unroll
    for (int mm = 1; mm <= 8; mm <<= 1) {
      lm0 = fmaxf(lm0, __shfl_xor(lm0, mm, 64));
      lm1 = fmaxf(lm1, __shfl_xor(lm1, mm, 64));
    }
    float mn0 = fmaxf(m0, lm0), mn1 = fmaxf(m1, lm1);
    float sc0 = expf(m0 - mn0), sc1 = expf(m1 - mn1);
    float p00 = expf(s00 - mn0), p01 = expf(s01 - mn0);
    float p02 = expf(s02 - mn0), p03 = expf(s03 - mn0);
    float p10 = expf(s10 - mn1), p11 = expf(s11 - mn1);
    float p12 = expf(s12 - mn1), p13 = expf(s13 - mn1);
    float ls0 = p00 + p01 + p02 + p03;
    float ls1 = p10 + p11 + p12 + p13;
#pragma unroll
    for (int mm = 1; mm <= 8; mm <<= 1) {
      ls0 += __shfl_xor(ls0, mm, 64);
      ls1 += __shfl_xor(ls1, mm, 64);
    }
    l0 = l0 * sc0 + ls0;
    l1 = l1 * sc1 + ls1;
    o0.x *= sc0; o0.y *= sc0; o0.z *= sc0; o0.w *= sc0;
    o1.x *= sc1; o1.y *= sc1; o1.z *= sc1; o1.w *= sc1;
    m0 = mn0; m1 = mn1;

    *reinterpret_cast<float4*>(&sP[2 * qp + 0][kg * 4]) = make_float4(p00, p01, p02, p03);
    *reinterpret_cast<float4*>(&sP[2 * qp + 1][kg * 4]) = make_float4(p10, p11, p12, p13);
    __syncthreads();

#pragma unroll
    for (int k4 = 0; k4 < 16; ++k4) {
      float4 pa = *reinterpret_cast<const float4*>(&sP[2 * qp + 0][k4 * 4]);
      float4 pb = *reinterpret_cast<const float4*>(&sP[2 * qp + 1][k4 * 4]);
#pragma unroll
      for (int e = 0; e < 4; ++e) {
        float4 vv = *reinterpret_cast<const float4*>(&sV[k4 * 4 + e][kg * 4]);
        float w0 = (e == 0) ? pa.x : (e == 1) ? pa.y : (e == 2) ? pa.z : pa.w;
        float w1 = (e == 0) ? pb.x : (e == 1) ? pb.y : (e == 2) ? pb.z : pb.w;
        o0.x += w0 * vv.x; o0.y += w0 * vv.y; o0.z += w0 * vv.z; o0.w += w0 * vv.w;
        o1.x += w1 * vv.x; o1.y += w1 * vv.y; o1.z += w1 * vv.z; o1.w += w1 * vv.w;
      }
    }
  }

  const float inv0 = 1.f / l0, inv1 = 1.f / l1;
  float4 r0 = make_float4(o0.x * inv0, o0.y * inv0, o0.z * inv0, o0.w * inv0);
  float4 r1 = make_float4(o1.x * inv1, o1.y * inv1, o1.z * inv1, o1.w * inv1);
  *reinterpret_cast<float4*>(attn_out + (size_t)qg0 * DMODEL + h * DHEAD + kg * 4) = r0;
  *reinterpret_cast<float4*>(attn_out + (size_t)qg1 * DMODEL + h * DHEAD + kg * 4) = r1;
}

// ---------------- split-K projection: partial ----------------
__global__ __launch_bounds__(256) void proj_partial_kernel(
    const float* __restrict__ A, const float* __restrict__ Bm,
    float* __restrict__ part) {
  __shared__ float sA[64][68];
  __shared__ float sB[64][68];
  const int tid = threadIdx.x;
  const int tr = tid >> 4, tc = tid & 15;
  const int col0 = blockIdx.x * 64, row0 = blockIdx.y * 64;
  const int z = blockIdx.z;
  const int kbase = z * 256;
  float acc[4][4];
#pragma unroll
  for (int i = 0; i < 4; ++i)
#pragma unroll
    for (int j = 0; j < 4; ++j) acc[i][j] = 0.f;

  for (int kt = 0; kt < 4; ++kt) {
    const int k0 = kbase + kt * 64;
    __syncthreads();
    {
      const float4* Ag = reinterpret_cast<const float4*>(A + (size_t)row0 * DMODEL + k0);
#pragma unroll
      for (int it = 0; it < 4; ++it) {
        int f = tid + it * 256;
        int r = f >> 4, c4 = f & 15;
        *reinterpret_cast<float4*>(&sA[r][c4 * 4]) = Ag[r * 256 + c4];
      }
      const float4* Bg = reinterpret_cast<const float4*>(Bm + (size_t)k0 * DMODEL + col0);
#pragma unroll
      for (int it = 0; it < 4; ++it) {
        int f = tid + it * 256;
        int r = f >> 4, c4 = f & 15;
        *reinterpret_cast<float4*>(&sB[r][c4 * 4]) = Bg[r * 256 + c4];
      }
    }
    __syncthreads();
#pragma unroll 4
    for (int kk = 0; kk < 64; ++kk) {
      float a0 = sA[tr * 4 + 0][kk], a1 = sA[tr * 4 + 1][kk];
      float a2 = sA[tr * 4 + 2][kk], a3 = sA[tr * 4 + 3][kk];
      float4 b = *reinterpret_cast<const float4*>(&sB[kk][tc * 4]);
      acc[0][0] += a0 * b.x; acc[0][1] += a0 * b.y; acc[0][2] += a0 * b.z; acc[0][3] += a0 * b.w;
      acc[1][0] += a1 * b.x; acc[1][1] += a1 * b.y; acc[1][2] += a1 * b.z; acc[1][3] += a1 * b.w;
      acc[2][0] += a2 * b.x; acc[2][1] += a2 * b.y; acc[2][2] += a2 * b.z; acc[2][3] += a2 * b.w;
      acc[3][0] += a3 * b.x; acc[3][1] += a3 * b.y; acc[3][2] += a3 * b.z; acc[3][3] += a3 * b.w;
    }
  }

  float* dst = part + (size_t)z * (DMODEL * S_TOK);
#pragma unroll
  for (int i = 0; i < 4; ++i) {
    *reinterpret_cast<float4*>(dst + (size_t)(row0 + tr * 4 + i) * DMODEL + col0 + tc * 4) =
        make_float4(acc[i][0], acc[i][1], acc[i][2], acc[i][3]);
  }
}

// ---------------- projection combine: H = x + sum_z part[z] ----------------
__global__ __launch_bounds__(256) void proj_combine_kernel(
    const float* __restrict__ part, const float* __restrict__ x,
    float* __restrict__ H) {
  const int i = blockIdx.x * 256 + threadIdx.x;
  const float4* p4 = reinterpret_cast<const float4*>(part);
  float4 p0 = p4[i];
  float4 p1 = p4[i + 262144];
  float4 p2 = p4[i + 524288];
  float4 p3 = p4[i + 786432];
  float4 xv = reinterpret_cast<const float4*>(x)[i];
  reinterpret_cast<float4*>(H)[i] =
      make_float4(xv.x + p0.x + p1.x + p2.x + p3.x, xv.y + p0.y + p1.y + p2.y + p3.y,
                  xv.z + p0.z + p1.z + p2.z + p3.z, xv.w + p0.w + p1.w + p2.w + p3.w);
}

// ---------------- fallback proj (small ws) ----------------
__global__ __launch_bounds__(256) void proj_add_kernel(
    const float* __restrict__ A, const float* __restrict__ Bm,
    const float* __restrict__ x, float* __restrict__ H) {
  __shared__ float sA[64][65];
  __shared__ float sB[64][65];
  const int tid = threadIdx.x;
  const int tr = tid >> 4, tc = tid & 15;
  const int row0 = blockIdx.y * 64, col0 = blockIdx.x * 64;
  float acc[4][4];
#pragma unroll
  for (int i = 0; i < 4; ++i)
#pragma unroll
    for (int j = 0; j < 4; ++j) acc[i][j] = 0.f;
  for (int kt = 0; kt < 16; ++kt) {
#pragma unroll
    for (int e = tid; e < 4096; e += 256) {
      int r = e >> 6, c = e & 63;
      sA[r][c] = A[(size_t)(row0 + r) * DMODEL + (kt * 64 + c)];
      sB[r][c] = Bm[(size_t)(kt * 64 + r) * DMODEL + (col0 + c)];
    }
    __syncthreads();
#pragma unroll 4
    for (int kk = 0; kk < 64; ++kk) {
      float a0 = sA[tr * 4 + 0][kk], a1 = sA[tr * 4 + 1][kk];
      float a2 = sA[tr * 4 + 2][kk], a3 = sA[tr * 4 + 3][kk];
      float b0 = sB[kk][tc * 4 + 0], b1 = sB[kk][tc * 4 + 1];
      float b2 = sB[kk][tc * 4 + 2], b3 = sB[kk][tc * 4 + 3];
      acc[0][0] += a0 * b0; acc[0][1] += a0 * b1; acc[0][2] += a0 * b2; acc[0][3] += a0 * b3;
      acc[1][0] += a1 * b0; acc[1][1] += a1 * b1; acc[1][2] += a1 * b2; acc[1][3] += a1 * b3;
      acc[2][0] += a2 * b0; acc[2][1] += a2 * b1; acc[2][2] += a2 * b2; acc[2][3] += a2 * b3;
      acc[3][0] += a3 * b0; acc[3][1] += a3 * b1; acc[3][2] += a3 * b2; acc[3][3] += a3 * b3;
    }
    __syncthreads();
  }
#pragma unroll
  for (int i = 0; i < 4; ++i) {
    size_t ro = (size_t)(row0 + tr * 4 + i) * DMODEL + col0 + tc * 4;
#pragma unroll
    for (int j = 0; j < 4; ++j) H[ro + j] = x[ro + j] + acc[i][j];
  }
}

// ---------------- know token kernel (pass-2 over gate survivors only) ----------------
__global__ __launch_bounds__(256) void know_token_kernel(
    const float* __restrict__ h, const float* __restrict__ tau,
    const float* __restrict__ know_neurons,
    const int* __restrict__ idxk, const float* __restrict__ dk,
    float* __restrict__ out, float* __restrict__ loss_acc) {
  const int s = blockIdx.x;
  const int tid = threadIdx.x;
  const int lane = tid & 63, wave = tid >> 6;
  __shared__ __align__(16) float s_h[DMODEL];
  __shared__ float s_act[128];
  __shared__ float s_eg[128];
  __shared__ float s_w[128];
  __shared__ float s_wg[128];
  __shared__ float s_g[128];
  __shared__ int s_idx[128];
  __shared__ int s_klist[128];
  __shared__ int s_wcnt[2];
  __shared__ int s_kcnt;
  __shared__ float s_kth, s_gsum, s_strength;

  for (int i = tid; i < DMODEL; i += 256) s_h[i] = h[(size_t)s * DMODEL + i];
  if (tid < 128) s_idx[tid] = idxk[s * 128 + tid];
  __syncthreads();

  const float4* h4 = reinterpret_cast<const float4*>(s_h);
  for (int c = wave * 32; c < wave * 32 + 32; ++c) {
    const float4* row4 = reinterpret_cast<const float4*>(know_neurons + (size_t)s_idx[c] * DMODEL);
    float acc = 0.f;
#pragma unroll
    for (int k = 0; k < 4; ++k) {
      float4 rv = row4[lane + k * 64];
      float4 xv = h4[lane + k * 64];
      acc += rv.x * xv.x + rv.y * xv.y + rv.z * xv.z + rv.w * xv.w;
    }
    acc = wave_reduce_sum(acc);
    if (lane == 0) s_act[c] = acc;
  }
  __syncthreads();

  const float tv = tau[s];
  if (tid < 128) {
    float a = s_act[tid];
    float raw = a - tv;
    float gate = (raw > 0.f) ? raw : 1e-8f * __expf(raw);
    s_eg[tid] = __expf(gate) - 1.f;
  }
  __syncthreads();
  if (tid < 128) {
    float e = s_eg[tid];
    int rank = 0;
    for (int j = 0; j < 128; ++j) {
      float ej = s_eg[j];
      rank += ((ej > e) || (ej == e && j < tid)) ? 1 : 0;
    }
    if (rank == 63) s_kth = e;
  }
  __syncthreads();
  if (tid < 128) {
    float e = s_eg[tid];
    s_w[tid] = (e >= s_kth) ? e : 0.f;
  }
  __syncthreads();
  if (wave == 0) {
    float sum = wave_reduce_sum(s_w[lane] + s_w[lane + 64]);
    float mx = wave_reduce_max(fmaxf(s_eg[lane], s_eg[lane + 64]));
    if (lane == 0) { s_gsum = sum + 1e-8f; s_strength = tanhf(mx); }
  }
  // survivor compaction phase 1: per-wave counts
  if (tid < 128) {
    bool pred = s_w[tid] != 0.f;
    unsigned long long m = __ballot(pred);
    if (lane == 0) s_wcnt[wave] = __popcll(m);
  }
  __syncthreads();
  if (tid < 128) {
    float g = s_w[tid] / s_gsum * s_strength;
    s_g[tid] = g;
    s_wg[tid] = s_act[tid] * g;
    bool pred = s_w[tid] != 0.f;
    unsigned long long m = __ballot(pred);
    int base = (wave == 1) ? s_wcnt[0] : 0;
    int pos = base + __popcll(m & ((1ull << lane) - 1ull));
    if (pred) s_klist[pos] = tid;
    if (tid == 0) s_kcnt = s_wcnt[0] + s_wcnt[1];
  }
  __syncthreads();
  if (wave == 0) {
    float pl = s_g[lane] * dk[s * 128 + lane] + s_g[lane + 64] * dk[s * 128 + lane + 64];
    pl = wave_reduce_sum(pl);
    if (lane == 0) atomicAdd(loss_acc, pl * (1.f / 131072.f));
  }

  const int d0 = tid * 4;
  const int kc = s_kcnt;
  float a0 = 0, a1 = 0, a2 = 0, a3 = 0;
  for (int j = 0; j < kc; ++j) {
    const int c = s_klist[j];
    const float4 r = *reinterpret_cast<const float4*>(know_neurons + (size_t)s_idx[c] * DMODEL + d0);
    const float wv = s_wg[c];
    a0 += wv * r.x; a1 += wv * r.y; a2 += wv * r.z; a3 += wv * r.w;
  }
  float h0 = s_h[d0 + 0], h1 = s_h[d0 + 1], h2 = s_h[d0 + 2], h3 = s_h[d0 + 3];
  *reinterpret_cast<float4*>(out + (size_t)s * DMODEL + d0) =
      make_float4(h0 + a0, h1 + a1, h2 + a2, h3 + a3);
}

extern "C" void kernel_launch(void* const* d_in, const int* in_sizes, int n_in,
                              void* d_out, int out_size, void* d_ws, size_t ws_size,
                              hipStream_t stream) {
  const float* x = (const float*)d_in[0];
  const float* qk_pos = (const float*)d_in[1];
  const float* v_pos = (const float*)d_in[2];
  const float* know_pos = (const float*)d_in[3];
  const float* tau_q = (const float*)d_in[4];
  const float* tau_k = (const float*)d_in[5];
  const float* tau_v = (const float*)d_in[6];
  const float* tau_know = (const float*)d_in[7];
  const float* qk_neurons = (const float*)d_in[8];
  const float* v_neurons = (const float*)d_in[9];
  const float* know_neurons = (const float*)d_in[10];
  const float* npos_qk = (const float*)d_in[11];
  const float* npos_v = (const float*)d_in[12];
  const float* npos_know = (const float*)d_in[13];
  const float* expand_O = (const float*)d_in[14];
  float* out = (float*)d_out;
  float* loss_acc = out + (size_t)S_TOK * DMODEL;

  char* w = (char*)d_ws;
  int* idx_qk = (int*)(w + 0);
  float* dist_qk = (float*)(w + 262144);
  int* idx_v = (int*)(w + 524288);
  float* dist_v = (float*)(w + 786432);
  int* idx_know = (int*)(w + 1048576);
  float* dist_know = (float*)(w + 1572864);
  float* Qb = (float*)(w + 2097152);
  float* Kb = (float*)(w + 6291456);
  float* Vb = (float*)(w + 10485760);
  float* attnbuf = (float*)(w + 14680064);
  float* hbuf = (float*)(w + 18874368);
  float* Rbuf = (float*)(w + 23068672);  // 16 MB scratch: selects -> attn partials -> proj partials

  hipMemsetAsync(loss_acc, 0, sizeof(float), stream);

  const bool big_ws = ws_size >= (size_t)23068672 + 16777216;
  if (big_ws) {
    rgemm_kernel<<<dim3(32, 16), 256, 0, stream>>>(qk_pos, npos_qk, Rbuf, 0, 4096);
    select2_kernel<4096, 64><<<1024, 256, 0, stream>>>(Rbuf, qk_pos, npos_qk, 0, idx_qk, dist_qk);
    rgemm_kernel<<<dim3(32, 16), 256, 0, stream>>>(v_pos, npos_v, Rbuf, 0, 4096);
    select2_kernel<4096, 64><<<1024, 256, 0, stream>>>(Rbuf, v_pos, npos_v, 0, idx_v, dist_v);
    rgemm_kernel<<<dim3(64, 8), 256, 0, stream>>>(know_pos, npos_know, Rbuf, 0, 8192);
    select2_kernel<8192, 128><<<512, 256, 0, stream>>>(Rbuf, know_pos, npos_know, 0, idx_know, dist_know);
    rgemm_kernel<<<dim3(64, 8), 256, 0, stream>>>(know_pos, npos_know, Rbuf, 512, 8192);
    select2_kernel<8192, 128><<<512, 256, 0, stream>>>(Rbuf, know_pos, npos_know, 512, idx_know, dist_know);
  } else {
    select_topk_fused_kernel<4096, 64><<<S_TOK, 256, 0, stream>>>(qk_pos, npos_qk, idx_qk, dist_qk);
    select_topk_fused_kernel<4096, 64><<<S_TOK, 256, 0, stream>>>(v_pos, npos_v, idx_v, dist_v);
    select_topk_fused_kernel<8192, 128><<<S_TOK, 256, 0, stream>>>(know_pos, npos_know, idx_know, dist_know);
  }

  attn_token_kernel<<<S_TOK, 256, 0, stream>>>(x, tau_q, tau_k, tau_v, qk_neurons, v_neurons,
                                               idx_qk, dist_qk, idx_v, dist_v, Qb, Kb, Vb, loss_acc);

  if (big_ws) {
    attention_partial_kernel<<<1280, 256, 0, stream>>>(Qb, Kb, Vb, Rbuf);
    attention_combine_kernel<<<512, 256, 0, stream>>>(Rbuf, attnbuf);
    proj_partial_kernel<<<dim3(16, 16, 4), 256, 0, stream>>>(attnbuf, expand_O, Rbuf);
    proj_combine_kernel<<<1024, 256, 0, stream>>>(Rbuf, x, hbuf);
  } else {
    attention_kernel<<<512, 256, 0, stream>>>(Qb, Kb, Vb, attnbuf);
    proj_add_kernel<<<dim3(16, 16), 256, 0, stream>>>(attnbuf, expand_O, x, hbuf);
  }

  know_token_kernel<<<S_TOK, 256, 0, stream>>>(hbuf, tau_know, know_neurons, idx_know, dist_know,
                                               out, loss_acc);
}

// Round 11
// 363.664 us; speedup vs baseline: 1.0772x; 1.0772x over previous
//
#include <hip/hip_runtime.h>
#include <math.h>

#define S_TOK 1024
#define DMODEL 1024
#define PDIM 32
#define NHEADS 16
#define DHEAD 64

__device__ __forceinline__ float wave_reduce_sum(float v) {
#pragma unroll
  for (int m = 32; m >= 1; m >>= 1) v += __shfl_xor(v, m, 64);
  return v;
}
__device__ __forceinline__ float wave_reduce_max(float v) {
#pragma unroll
  for (int m = 32; m >= 1; m >>= 1) v = fmaxf(v, __shfl_xor(v, m, 64));
  return v;
}
__device__ __forceinline__ float wave_reduce_min(float v) {
#pragma unroll
  for (int m = 32; m >= 1; m >>= 1) v = fminf(v, __shfl_xor(v, m, 64));
  return v;
}

#define NBINS 4096
#define CAND_MAX 512

// ---------------- r-GEMM: R[s, n] = ||n||^2 - 2 * p_s . n ----------------
__global__ __launch_bounds__(256) void rgemm_kernel(
    const float* __restrict__ pos, const float* __restrict__ npos,
    float* __restrict__ R, int s0, int N) {
  __shared__ float sAT[32][68];
  __shared__ float sBT[32][2][68];
  __shared__ float s_nrm[128];
  const int tid = threadIdx.x;
  const int n0 = blockIdx.x * 128;
  const int t0 = blockIdx.y * 64;

  {
    const float4* g = reinterpret_cast<const float4*>(pos + (size_t)(s0 + t0) * PDIM);
#pragma unroll
    for (int i = 0; i < 2; ++i) {
      int f = tid + i * 256;
      float4 v = g[f];
      int t = f >> 3, ks = (f & 7) * 4;
      sAT[ks + 0][t] = v.x; sAT[ks + 1][t] = v.y;
      sAT[ks + 2][t] = v.z; sAT[ks + 3][t] = v.w;
    }
    const float4* gb = reinterpret_cast<const float4*>(npos + (size_t)n0 * PDIM);
#pragma unroll
    for (int i = 0; i < 4; ++i) {
      int f = tid + i * 256;
      float4 v = gb[f];
      int n = f >> 3, ks = (f & 7) * 4;
      int hh = n >> 6, m = n & 63;
      sBT[ks + 0][hh][m] = v.x; sBT[ks + 1][hh][m] = v.y;
      sBT[ks + 2][hh][m] = v.z; sBT[ks + 3][hh][m] = v.w;
    }
  }
  __syncthreads();
  if (tid < 128) {
    int hh = tid >> 6, m = tid & 63;
    float acc = 0.f;
#pragma unroll
    for (int k = 0; k < 32; ++k) { float b = sBT[k][hh][m]; acc += b * b; }
    s_nrm[tid] = acc;
  }
  __syncthreads();

  const int tt = tid >> 4, nn = tid & 15;
  float acc[4][8];
#pragma unroll
  for (int i = 0; i < 4; ++i)
#pragma unroll
    for (int j = 0; j < 8; ++j) acc[i][j] = 0.f;

#pragma unroll 8
  for (int k = 0; k < 32; ++k) {
    const float4 a = *reinterpret_cast<const float4*>(&sAT[k][tt * 4]);
    const float4 b0 = *reinterpret_cast<const float4*>(&sBT[k][0][nn * 4]);
    const float4 b1 = *reinterpret_cast<const float4*>(&sBT[k][1][nn * 4]);
    const float av[4] = {a.x, a.y, a.z, a.w};
#pragma unroll
    for (int t = 0; t < 4; ++t) {
      acc[t][0] += av[t] * b0.x; acc[t][1] += av[t] * b0.y;
      acc[t][2] += av[t] * b0.z; acc[t][3] += av[t] * b0.w;
      acc[t][4] += av[t] * b1.x; acc[t][5] += av[t] * b1.y;
      acc[t][6] += av[t] * b1.z; acc[t][7] += av[t] * b1.w;
    }
  }

  const float n00 = s_nrm[nn * 4 + 0], n01 = s_nrm[nn * 4 + 1];
  const float n02 = s_nrm[nn * 4 + 2], n03 = s_nrm[nn * 4 + 3];
  const float n10 = s_nrm[64 + nn * 4 + 0], n11 = s_nrm[64 + nn * 4 + 1];
  const float n12 = s_nrm[64 + nn * 4 + 2], n13 = s_nrm[64 + nn * 4 + 3];
#pragma unroll
  for (int t = 0; t < 4; ++t) {
    const size_t ro = (size_t)(t0 + tt * 4 + t) * N + n0;
    float4 r0 = make_float4(fmaf(-2.f, acc[t][0], n00), fmaf(-2.f, acc[t][1], n01),
                            fmaf(-2.f, acc[t][2], n02), fmaf(-2.f, acc[t][3], n03));
    float4 r1 = make_float4(fmaf(-2.f, acc[t][4], n10), fmaf(-2.f, acc[t][5], n11),
                            fmaf(-2.f, acc[t][6], n12), fmaf(-2.f, acc[t][7], n13));
    *reinterpret_cast<float4*>(R + ro + nn * 4) = r0;
    *reinterpret_cast<float4*>(R + ro + 64 + nn * 4) = r1;
  }
}

// ---------------- slim select on precomputed R row ----------------
template <int N, int K>
__global__ __launch_bounds__(256) void select2_kernel(
    const float* __restrict__ R, const float* __restrict__ pos,
    const float* __restrict__ npos, int s0,
    int* __restrict__ out_idx, float* __restrict__ out_dist) {
  const int bid = blockIdx.x;
  const int s = s0 + bid;
  const int tid = threadIdx.x;
  const int lane = tid & 63;
  const int wave = tid >> 6;

  __shared__ float s_dist[N];
  __shared__ unsigned s_hist[NBINS];
  __shared__ unsigned s_part[256];
  __shared__ float4 s_p4[8];
  __shared__ float s_red[16];
  __shared__ float s_lo, s_scale;
  __shared__ int s_B, s_need, s_cnt, s_ccnt;
  __shared__ int s_selidx[K];
  __shared__ float s_seldist[K];
  __shared__ int s_cidx[CAND_MAX];
  __shared__ float s_cdist[CAND_MAX];

  if (tid < 8) s_p4[tid] = reinterpret_cast<const float4*>(pos + (size_t)s * PDIM)[tid];
  for (int j = tid; j < K; j += 256) s_selidx[j] = 0;
  for (int b = tid; b < NBINS; b += 256) s_hist[b] = 0u;
  __syncthreads();

  float lmin = 3.0e38f, lmax = -3.0e38f;
  const float* row = R + (size_t)bid * N;
#pragma unroll 4
  for (int i = 0; i < N / 256; ++i) {
    float v = row[tid + i * 256];
    s_dist[tid + i * 256] = v;
    lmin = fminf(lmin, v);
    lmax = fmaxf(lmax, v);
  }
  lmin = wave_reduce_min(lmin);
  lmax = wave_reduce_max(lmax);
  if (lane == 0) { s_red[wave] = lmin; s_red[8 + wave] = lmax; }
  __syncthreads();
  if (tid == 0) {
    float lo = s_red[0], hi = s_red[8];
    for (int w2 = 1; w2 < 4; ++w2) {
      lo = fminf(lo, s_red[w2]);
      hi = fmaxf(hi, s_red[8 + w2]);
    }
    s_lo = lo;
    s_scale = (float)NBINS / fmaxf(hi - lo, 1e-30f);
  }
  __syncthreads();

  const float lo = s_lo, scale = s_scale;
  for (int n = tid; n < N; n += 256) {
    int b = min(NBINS - 1, (int)((s_dist[n] - lo) * scale));
    atomicAdd(&s_hist[b], 1u);
  }
  __syncthreads();

  unsigned psum = 0;
#pragma unroll 4
  for (int b = tid * 16; b < tid * 16 + 16; ++b) psum += s_hist[b];
  s_part[tid] = psum;
  __syncthreads();
  if (tid == 0) {
    unsigned cum = 0;
    int c = 0;
    for (; c < 256; ++c) {
      unsigned pc = s_part[c];
      if (cum + pc >= (unsigned)K) break;
      cum += pc;
    }
    int b = c * 16;
    for (;; ++b) {
      unsigned cb = s_hist[b];
      if (cum + cb >= (unsigned)K) break;
      cum += cb;
    }
    s_B = b;
    s_need = K - (int)cum;
    s_cnt = 0;
    s_ccnt = 0;
  }
  __syncthreads();

  const int B = s_B;
  for (int n = tid; n < N; n += 256) {
    float d = s_dist[n];
    int b = min(NBINS - 1, (int)((d - lo) * scale));
    if (b < B) {
      int p = atomicAdd(&s_cnt, 1);
      s_selidx[p] = n;
    } else if (b == B) {
      int e = atomicAdd(&s_ccnt, 1);
      if (e < CAND_MAX) { s_cidx[e] = n; s_cdist[e] = d; }
    }
  }
  __syncthreads();

  const int M = s_ccnt < CAND_MAX ? s_ccnt : CAND_MAX;
  const int need = s_need;
  const int base = s_cnt;
  for (int i = tid; i < M; i += 256) {
    float di = s_cdist[i];
    int idxi = s_cidx[i];
    int rank = 0;
    for (int j = 0; j < M; ++j) {
      float dj = s_cdist[j];
      rank += (dj < di || (dj == di && s_cidx[j] < idxi)) ? 1 : 0;
    }
    if (rank < need) s_selidx[base + rank] = idxi;
  }
  __syncthreads();

  {
    const int g = tid >> 3, sl = tid & 7;
    const float4 pv = s_p4[sl];
    for (int j = g; j < K; j += 32) {
      const float4 nv =
          *reinterpret_cast<const float4*>(npos + (size_t)s_selidx[j] * PDIM + sl * 4);
      float dx = pv.x - nv.x, dy = pv.y - nv.y, dz = pv.z - nv.z, dw = pv.w - nv.w;
      float d = dx * dx + dy * dy + dz * dz + dw * dw;
      d += __shfl_xor(d, 1, 64);
      d += __shfl_xor(d, 2, 64);
      d += __shfl_xor(d, 4, 64);
      if (sl == 0) s_seldist[j] = d;
    }
  }
  __syncthreads();
  for (int j = tid; j < K; j += 256) {
    out_idx[(size_t)s * K + j] = s_selidx[j];
    out_dist[(size_t)s * K + j] = s_seldist[j];
  }
}

// ---------------- fallback: fused distance+select ----------------
template <int N, int K>
__global__ __launch_bounds__(256) void select_topk_fused_kernel(
    const float* __restrict__ pos, const float* __restrict__ npos,
    int* __restrict__ out_idx, float* __restrict__ out_dist) {
  const int s = blockIdx.x;
  const int tid = threadIdx.x;
  const int lane = tid & 63;
  const int wave = tid >> 6;
  const int sl = lane & 7;
  const int rw = lane >> 3;

  __shared__ float s_dist[N];
  __shared__ unsigned s_hist[NBINS];
  __shared__ unsigned s_part[256];
  __shared__ float4 s_p4[8];
  __shared__ float s_red[16];
  __shared__ float s_lo, s_scale;
  __shared__ int s_B, s_need;
  __shared__ int s_cnt, s_ccnt;
  __shared__ int s_selidx[K];
  __shared__ float s_seldist[K];
  __shared__ int s_cidx[CAND_MAX];
  __shared__ float s_cdist[CAND_MAX];

  if (tid < 8) s_p4[tid] = reinterpret_cast<const float4*>(pos + (size_t)s * PDIM)[tid];
  for (int j = tid; j < K; j += 256) { s_selidx[j] = 0; s_seldist[j] = 0.f; }
  for (int b = tid; b < NBINS; b += 256) s_hist[b] = 0u;
  __syncthreads();

  const float4 pv = s_p4[sl];
  float lmin = 3.0e38f, lmax = -3.0e38f;
  const int rows_per_wave = N / 4;
  const int rbase = wave * rows_per_wave;
  for (int it = 0; it < rows_per_wave; it += 16) {
    const int ra = rbase + it + rw;
    const int rb = ra + 8;
    const float4 na = *reinterpret_cast<const float4*>(npos + (size_t)ra * PDIM + sl * 4);
    const float4 nb = *reinterpret_cast<const float4*>(npos + (size_t)rb * PDIM + sl * 4);
    float dax = pv.x - na.x, day = pv.y - na.y, daz = pv.z - na.z, daw = pv.w - na.w;
    float dbx = pv.x - nb.x, dby = pv.y - nb.y, dbz = pv.z - nb.z, dbw = pv.w - nb.w;
    float da = dax * dax + day * day + daz * daz + daw * daw;
    float db = dbx * dbx + dby * dby + dbz * dbz + dbw * dbw;
    da += __shfl_xor(da, 1, 64); da += __shfl_xor(da, 2, 64); da += __shfl_xor(da, 4, 64);
    db += __shfl_xor(db, 1, 64); db += __shfl_xor(db, 2, 64); db += __shfl_xor(db, 4, 64);
    lmin = fminf(lmin, fminf(da, db));
    lmax = fmaxf(lmax, fmaxf(da, db));
    if (sl == 0) { s_dist[ra] = da; s_dist[rb] = db; }
  }
  lmin = wave_reduce_min(lmin);
  lmax = wave_reduce_max(lmax);
  if (lane == 0) { s_red[wave] = lmin; s_red[8 + wave] = lmax; }
  __syncthreads();
  if (tid == 0) {
    float lo = s_red[0], hi = s_red[8];
    for (int w2 = 1; w2 < 4; ++w2) {
      lo = fminf(lo, s_red[w2]);
      hi = fmaxf(hi, s_red[8 + w2]);
    }
    s_lo = lo;
    s_scale = (float)NBINS / fmaxf(hi - lo, 1e-30f);
  }
  __syncthreads();

  const float lo = s_lo, scale = s_scale;
  for (int n = tid; n < N; n += 256) {
    int b = min(NBINS - 1, (int)((s_dist[n] - lo) * scale));
    atomicAdd(&s_hist[b], 1u);
  }
  __syncthreads();

  unsigned psum = 0;
#pragma unroll 4
  for (int b = tid * 16; b < tid * 16 + 16; ++b) psum += s_hist[b];
  s_part[tid] = psum;
  __syncthreads();
  if (tid == 0) {
    unsigned cum = 0;
    int c = 0;
    for (; c < 256; ++c) {
      unsigned pc = s_part[c];
      if (cum + pc >= (unsigned)K) break;
      cum += pc;
    }
    int b = c * 16;
    for (;; ++b) {
      unsigned cb = s_hist[b];
      if (cum + cb >= (unsigned)K) break;
      cum += cb;
    }
    s_B = b;
    s_need = K - (int)cum;
    s_cnt = 0;
    s_ccnt = 0;
  }
  __syncthreads();

  const int B = s_B;
  for (int n = tid; n < N; n += 256) {
    float d = s_dist[n];
    int b = min(NBINS - 1, (int)((d - lo) * scale));
    if (b < B) {
      int p = atomicAdd(&s_cnt, 1);
      s_selidx[p] = n;
      s_seldist[p] = d;
    } else if (b == B) {
      int e = atomicAdd(&s_ccnt, 1);
      if (e < CAND_MAX) { s_cidx[e] = n; s_cdist[e] = d; }
    }
  }
  __syncthreads();

  const int M = s_ccnt < CAND_MAX ? s_ccnt : CAND_MAX;
  const int need = s_need;
  const int base = s_cnt;
  for (int i = tid; i < M; i += 256) {
    unsigned ki = __float_as_uint(s_cdist[i]);
    int idxi = s_cidx[i];
    int rank = 0;
    for (int j = 0; j < M; ++j) {
      unsigned kj = __float_as_uint(s_cdist[j]);
      rank += (kj < ki || (kj == ki && s_cidx[j] < idxi)) ? 1 : 0;
    }
    if (rank < need) {
      s_selidx[base + rank] = idxi;
      s_seldist[base + rank] = s_cdist[i];
    }
  }
  __syncthreads();

  for (int j = tid; j < K; j += 256) {
    out_idx[(size_t)s * K + j] = s_selidx[j];
    out_dist[(size_t)s * K + j] = s_seldist[j];
  }
}

// ---------------- attn token kernel (pass-2 over gate survivors only) ----------------
__global__ __launch_bounds__(256) void attn_token_kernel(
    const float* __restrict__ x,
    const float* __restrict__ tau_q, const float* __restrict__ tau_k,
    const float* __restrict__ tau_v,
    const float* __restrict__ qk_neurons, const float* __restrict__ v_neurons,
    const int* __restrict__ idx_qk, const float* __restrict__ d_qk,
    const int* __restrict__ idx_v, const float* __restrict__ d_v,
    float* __restrict__ Qh, float* __restrict__ Kh, float* __restrict__ Vh,
    float* __restrict__ loss_acc) {
  const int s = blockIdx.x;
  const int tid = threadIdx.x;
  const int lane = tid & 63;
  const int wave = tid >> 6;
  __shared__ __align__(16) float s_x[DMODEL];
  __shared__ float s_act_qk[64], s_act_v[64];
  __shared__ float s_wq[64], s_wk[64], s_wv[64];
  __shared__ float s_gq[64], s_gv[64];
  __shared__ int s_iqk[64], s_iv[64];
  __shared__ int s_qklist[64], s_vlist[64];
  __shared__ int s_qkcnt, s_vcnt;

  for (int i = tid; i < DMODEL; i += 256) s_x[i] = x[(size_t)s * DMODEL + i];
  if (tid < 64) {
    s_iqk[tid] = idx_qk[s * 64 + tid];
    s_iv[tid] = idx_v[s * 64 + tid];
  }
  __syncthreads();

  const float4* x4 = reinterpret_cast<const float4*>(s_x);
  for (int c = wave * 16; c < wave * 16 + 16; ++c) {
    const float4* row4 = reinterpret_cast<const float4*>(qk_neurons + (size_t)s_iqk[c] * DMODEL);
    float acc = 0.f;
#pragma unroll
    for (int k = 0; k < 4; ++k) {
      float4 rv = row4[lane + k * 64];
      float4 xv = x4[lane + k * 64];
      acc += rv.x * xv.x + rv.y * xv.y + rv.z * xv.z + rv.w * xv.w;
    }
    acc = wave_reduce_sum(acc);
    if (lane == 0) s_act_qk[c] = acc;
  }
  for (int c = wave * 16; c < wave * 16 + 16; ++c) {
    const float4* row4 = reinterpret_cast<const float4*>(v_neurons + (size_t)s_iv[c] * DMODEL);
    float acc = 0.f;
#pragma unroll
    for (int k = 0; k < 4; ++k) {
      float4 rv = row4[lane + k * 64];
      float4 xv = x4[lane + k * 64];
      acc += rv.x * xv.x + rv.y * xv.y + rv.z * xv.z + rv.w * xv.w;
    }
    acc = wave_reduce_sum(acc);
    if (lane == 0) s_act_v[c] = acc;
  }
  __syncthreads();

  if (wave < 3) {
    const float a = (wave == 2) ? s_act_v[lane] : s_act_qk[lane];
    const float tau = (wave == 0) ? tau_q[s] : (wave == 1) ? tau_k[s] : tau_v[s];
    float raw = a - tau;
    float gate = (raw > 0.f) ? raw : 1e-8f * __expf(raw);
    float eg = __expf(gate) - 1.f;
    int rank = 0;
    for (int j = 0; j < 64; ++j) {
      float vj = __shfl(eg, j, 64);
      rank += ((vj > eg) || (vj == eg && j < lane)) ? 1 : 0;
    }
    unsigned long long bm = __ballot(rank == 31);
    int srcl = __ffsll(bm) - 1;
    float kthv = __shfl(eg, srcl, 64);
    float w = (eg >= kthv) ? eg : 0.f;
    float gsum = wave_reduce_sum(w) + 1e-8f;
    float strength = tanhf(wave_reduce_max(eg));
    float g = w / gsum * strength;
    if (wave == 0) { s_wq[lane] = a * g; s_gq[lane] = g; }
    else if (wave == 1) { s_wk[lane] = a * g; }
    else { s_wv[lane] = a * g; s_gv[lane] = g; }
  }
  __syncthreads();

  // survivor compaction (deterministic, index-ordered)
  if (wave == 0) {
    bool pred = (s_wq[lane] != 0.f) || (s_wk[lane] != 0.f);
    unsigned long long m = __ballot(pred);
    int pos = __popcll(m & ((1ull << lane) - 1ull));
    if (pred) s_qklist[pos] = lane;
    if (lane == 0) s_qkcnt = __popcll(m);
  } else if (wave == 1) {
    bool pred = (s_wv[lane] != 0.f);
    unsigned long long m = __ballot(pred);
    int pos = __popcll(m & ((1ull << lane) - 1ull));
    if (pred) s_vlist[pos] = lane;
    if (lane == 0) s_vcnt = __popcll(m);
  } else if (wave == 2) {
    float pl = s_gq[lane] * d_qk[s * 64 + lane] + s_gv[lane] * d_v[s * 64 + lane];
    pl = wave_reduce_sum(pl);
    if (lane == 0) atomicAdd(loss_acc, pl * (1.f / 65536.f));
  }
  __syncthreads();

  // pass 2 over survivors only (skipped rows have exactly-zero weight)
  const int d0 = tid * 4;
  const int nqk = s_qkcnt, nv = s_vcnt;
  float aq0 = 0, aq1 = 0, aq2 = 0, aq3 = 0;
  float ak0 = 0, ak1 = 0, ak2 = 0, ak3 = 0;
  float av0 = 0, av1 = 0, av2 = 0, av3 = 0;
  for (int j = 0; j < nqk; ++j) {
    const int c = s_qklist[j];
    const float4 r = *reinterpret_cast<const float4*>(qk_neurons + (size_t)s_iqk[c] * DMODEL + d0);
    const float wq = s_wq[c], wk = s_wk[c];
    aq0 += wq * r.x; aq1 += wq * r.y; aq2 += wq * r.z; aq3 += wq * r.w;
    ak0 += wk * r.x; ak1 += wk * r.y; ak2 += wk * r.z; ak3 += wk * r.w;
  }
  for (int j = 0; j < nv; ++j) {
    const int c = s_vlist[j];
    const float4 r = *reinterpret_cast<const float4*>(v_neurons + (size_t)s_iv[c] * DMODEL + d0);
    const float wv = s_wv[c];
    av0 += wv * r.x; av1 += wv * r.y; av2 += wv * r.z; av3 += wv * r.w;
  }
  const int hh = d0 >> 6;
  const int dh = d0 & 63;
  const size_t base = ((size_t)hh * S_TOK + s) * DHEAD + dh;
  *reinterpret_cast<float4*>(Qh + base) = make_float4(aq0, aq1, aq2, aq3);
  *reinterpret_cast<float4*>(Kh + base) = make_float4(ak0, ak1, ak2, ak3);
  *reinterpret_cast<float4*>(Vh + base) = make_float4(av0, av1, av2, av3);
}

// ---------------- split-K attention: partial kernel (round-8 structure + __expf) ----------
// block -> (h, qt, chunk of 256 keys); slot: o[32][64], m[32], l[32] = 2112 floats.
__global__ __launch_bounds__(256) void attention_partial_kernel(
    const float* __restrict__ Q, const float* __restrict__ K,
    const float* __restrict__ V, float* __restrict__ part) {
  __shared__ float sQ[32][68];
  __shared__ float sKT[64][68];
  __shared__ float sV[64][68];
  __shared__ float sP[32][68];

  const int tid = threadIdx.x;
  const int bid = blockIdx.x;
  const int sw = (bid & 7) * 160 + (bid >> 3);  // XCD-contiguous
  const int h = sw / 80;
  const int r80 = sw % 80;
  int qt, c;
  if (r80 < 8) { qt = r80; c = 0; }
  else if (r80 < 24) { qt = 8 + ((r80 - 8) >> 1); c = (r80 - 8) & 1; }
  else if (r80 < 48) { qt = 16 + (r80 - 24) / 3; c = (r80 - 24) % 3; }
  else { qt = 24 + ((r80 - 48) >> 2); c = (r80 - 48) & 3; }
  const int q0 = qt * 32;
  const int kstart = c * 256;
  const int kend = min((qt + 1) * 32, kstart + 256);
  const int ntiles = (kend - kstart + 63) >> 6;
  const int g = qt >> 3;
  const int sbase = qt + 4 * g * (g - 1) + (qt - 8 * g) * g;
  float* slot = part + ((size_t)h * 80 + sbase + c) * 2112;

  const int qp = tid >> 4;
  const int kg = tid & 15;

  const float* Qb = Q + (size_t)h * S_TOK * DHEAD;
  const float* Kb = K + (size_t)h * S_TOK * DHEAD;
  const float* Vb = V + (size_t)h * S_TOK * DHEAD;

  {
    const float4* Qg4 = reinterpret_cast<const float4*>(Qb + (size_t)q0 * DHEAD);
    for (int f = tid; f < 512; f += 256) {
      float4 v = Qg4[f];
      int row = f >> 4, c4 = f & 15;
      float* dst = &sQ[row][c4 * 4];
      dst[0] = v.x * 0.125f; dst[1] = v.y * 0.125f;
      dst[2] = v.z * 0.125f; dst[3] = v.w * 0.125f;
    }
  }

  float m0 = -3.0e38f, m1 = -3.0e38f, l0 = 0.f, l1 = 0.f;
  float4 o0 = make_float4(0.f, 0.f, 0.f, 0.f);
  float4 o1 = make_float4(0.f, 0.f, 0.f, 0.f);

  const int qg0 = q0 + 2 * qp, qg1 = qg0 + 1;

  for (int t = 0; t < ntiles; ++t) {
    const int k0 = kstart + t * 64;
    __syncthreads();
    {
      const float4* Kg4 = reinterpret_cast<const float4*>(Kb + (size_t)k0 * DHEAD);
      for (int it = 0; it < 4; ++it) {
        int f = tid + it * 256;
        int row = f & 63;
        int c4 = f >> 6;
        float4 v = Kg4[row * 16 + c4];
        sKT[c4 * 4 + 0][row] = v.x; sKT[c4 * 4 + 1][row] = v.y;
        sKT[c4 * 4 + 2][row] = v.z; sKT[c4 * 4 + 3][row] = v.w;
      }
      const float4* Vg4 = reinterpret_cast<const float4*>(Vb + (size_t)k0 * DHEAD);
      for (int it = 0; it < 4; ++it) {
        int f = tid + it * 256;
        int row = f >> 4, c4 = f & 15;
        *reinterpret_cast<float4*>(&sV[row][c4 * 4]) = Vg4[f];
      }
    }
    __syncthreads();

    // ---- scores: rows {2qp, 2qp+1} x keys {4kg..4kg+3} ----
    float s00 = 0, s01 = 0, s02 = 0, s03 = 0;
    float s10 = 0, s11 = 0, s12 = 0, s13 = 0;
#pragma unroll
    for (int d4 = 0; d4 < 16; ++d4) {
      float4 qv0 = *reinterpret_cast<const float4*>(&sQ[2 * qp + 0][d4 * 4]);
      float4 qv1 = *reinterpret_cast<const float4*>(&sQ[2 * qp + 1][d4 * 4]);
#pragma unroll
      for (int e = 0; e < 4; ++e) {
        float4 kv = *reinterpret_cast<const float4*>(&sKT[d4 * 4 + e][kg * 4]);
        float qa = (e == 0) ? qv0.x : (e == 1) ? qv0.y : (e == 2) ? qv0.z : qv0.w;
        float qb = (e == 0) ? qv1.x : (e == 1) ? qv1.y : (e == 2) ? qv1.z : qv1.w;
        s00 += qa * kv.x; s01 += qa * kv.y; s02 += qa * kv.z; s03 += qa * kv.w;
        s10 += qb * kv.x; s11 += qb * kv.y; s12 += qb * kv.z; s13 += qb * kv.w;
      }
    }
    // causal mask
    const int kb = k0 + kg * 4;
    if (kb + 0 > qg0) s00 = -3.0e38f;
    if (kb + 1 > qg0) s01 = -3.0e38f;
    if (kb + 2 > qg0) s02 = -3.0e38f;
    if (kb + 3 > qg0) s03 = -3.0e38f;
    if (kb + 0 > qg1) s10 = -3.0e38f;
    if (kb + 1 > qg1) s11 = -3.0e38f;
    if (kb + 2 > qg1) s12 = -3.0e38f;
    if (kb + 3 > qg1) s13 = -3.0e38f;

    // online softmax: row stats across the 16-lane group sharing qp
    float lm0 = fmaxf(fmaxf(s00, s01), fmaxf(s02, s03));
    float lm1 = fmaxf(fmaxf(s10, s11), fmaxf(s12, s13));
#pragma unroll
    for (int mm = 1; mm <= 8; mm <<= 1) {
      lm0 = fmaxf(lm0, __shfl_xor(lm0, mm, 64));
      lm1 = fmaxf(lm1, __shfl_xor(lm1, mm, 64));
    }
    float mn0 = fmaxf(m0, lm0), mn1 = fmaxf(m1, lm1);
    float sc0 = __expf(m0 - mn0), sc1 = __expf(m1 - mn1);
    float p00 = __expf(s00 - mn0), p01 = __expf(s01 - mn0);
    float p02 = __expf(s02 - mn0), p03 = __expf(s03 - mn0);
    float p10 = __expf(s10 - mn1), p11 = __expf(s11 - mn1);
    float p12 = __expf(s12 - mn1), p13 = __expf(s13 - mn1);
    float ls0 = p00 + p01 + p02 + p03;
    float ls1 = p10 + p11 + p12 + p13;
#pragma unroll
    for (int mm = 1; mm <= 8; mm <<= 1) {
      ls0 += __shfl_xor(ls0, mm, 64);
      ls1 += __shfl_xor(ls1, mm, 64);
    }
    l0 = l0 * sc0 + ls0;
    l1 = l1 * sc1 + ls1;
    o0.x *= sc0; o0.y *= sc0; o0.z *= sc0; o0.w *= sc0;
    o1.x *= sc1; o1.y *= sc1; o1.z *= sc1; o1.w *= sc1;
    m0 = mn0; m1 = mn1;

    *reinterpret_cast<float4*>(&sP[2 * qp + 0][kg * 4]) = make_float4(p00, p01, p02, p03);
    *reinterpret_cast<float4*>(&sP[2 * qp + 1][kg * 4]) = make_float4(p10, p11, p12, p13);
    __syncthreads();

    // ---- PV: rows {2qp,2qp+1} x dims {4kg..4kg+3}, over 64 keys ----
#pragma unroll
    for (int k4 = 0; k4 < 16; ++k4) {
      float4 pa = *reinterpret_cast<const float4*>(&sP[2 * qp + 0][k4 * 4]);
      float4 pb = *reinterpret_cast<const float4*>(&sP[2 * qp + 1][k4 * 4]);
#pragma unroll
      for (int e = 0; e < 4; ++e) {
        float4 vv = *reinterpret_cast<const float4*>(&sV[k4 * 4 + e][kg * 4]);
        float w0 = (e == 0) ? pa.x : (e == 1) ? pa.y : (e == 2) ? pa.z : pa.w;
        float w1 = (e == 0) ? pb.x : (e == 1) ? pb.y : (e == 2) ? pb.z : pb.w;
        o0.x += w0 * vv.x; o0.y += w0 * vv.y; o0.z += w0 * vv.z; o0.w += w0 * vv.w;
        o1.x += w1 * vv.x; o1.y += w1 * vv.y; o1.z += w1 * vv.z; o1.w += w1 * vv.w;
      }
    }
  }

  *reinterpret_cast<float4*>(slot + (2 * qp + 0) * 64 + kg * 4) = o0;
  *reinterpret_cast<float4*>(slot + (2 * qp + 1) * 64 + kg * 4) = o1;
  if (kg == 0) {
    slot[2048 + 2 * qp + 0] = m0;
    slot[2048 + 2 * qp + 1] = m1;
    slot[2080 + 2 * qp + 0] = l0;
    slot[2080 + 2 * qp + 1] = l1;
  }
}

// ---------------- split-K attention: combine ----------------
__global__ __launch_bounds__(256) void attention_combine_kernel(
    const float* __restrict__ part, float* __restrict__ attn_out) {
  const int bid = blockIdx.x;  // 512 = h*32 + qt
  const int h = bid >> 5, qt = bid & 31;
  const int g = qt >> 3;
  const int sbase = qt + 4 * g * (g - 1) + (qt - 8 * g) * g;
  const int nc = g + 1;
  const float* P0 = part + ((size_t)h * 80 + sbase) * 2112;
  const int tid = threadIdx.x;
  const int r = tid >> 3, dg = tid & 7;

  float mstar = -3.0e38f;
  for (int c2 = 0; c2 < nc; ++c2) mstar = fmaxf(mstar, P0[c2 * 2112 + 2048 + r]);
  float a0 = 0, a1 = 0, a2 = 0, a3 = 0, a4 = 0, a5 = 0, a6 = 0, a7 = 0;
  float lsum = 0.f;
  for (int c2 = 0; c2 < nc; ++c2) {
    const float* S = P0 + c2 * 2112;
    float f = __expf(S[2048 + r] - mstar);
    lsum += S[2080 + r] * f;
    const float4* o4 = reinterpret_cast<const float4*>(S + r * 64 + dg * 8);
    float4 u = o4[0], v = o4[1];
    a0 += u.x * f; a1 += u.y * f; a2 += u.z * f; a3 += u.w * f;
    a4 += v.x * f; a5 += v.y * f; a6 += v.z * f; a7 += v.w * f;
  }
  const float inv = 1.f / lsum;
  float* dst = attn_out + (size_t)(qt * 32 + r) * DMODEL + h * DHEAD + dg * 8;
  *reinterpret_cast<float4*>(dst) = make_float4(a0 * inv, a1 * inv, a2 * inv, a3 * inv);
  *reinterpret_cast<float4*>(dst + 4) = make_float4(a4 * inv, a5 * inv, a6 * inv, a7 * inv);
}

// ---------------- fallback single-pass attention (small ws) ----------------
__global__ __launch_bounds__(256) void attention_kernel(
    const float* __restrict__ Q, const float* __restrict__ K,
    const float* __restrict__ V, float* __restrict__ attn_out) {
  __shared__ float sQ[32][68];
  __shared__ float sKT[64][68];
  __shared__ float sV[64][68];
  __shared__ float sP[32][68];

  const int tid = threadIdx.x;
  const int bid = blockIdx.x;
  const int xcd = bid & 7;
  const int slot = bid >> 3;
  const int h = xcd + 8 * (slot >> 5);
  const int w = slot & 31;
  const int phase = w >> 4;
  const int j0 = w & 15;
  const int qt = phase ? (31 - j0) : j0;
  const int q0 = qt * 32;
  const int ntiles = (qt + 2) >> 1;

  const int qp = tid >> 4;
  const int kg = tid & 15;

  const float* Qb = Q + (size_t)h * S_TOK * DHEAD;
  const float* Kb = K + (size_t)h * S_TOK * DHEAD;
  const float* Vb = V + (size_t)h * S_TOK * DHEAD;

  {
    const float4* Qg4 = reinterpret_cast<const float4*>(Qb + (size_t)q0 * DHEAD);
    for (int f = tid; f < 512; f += 256) {
      float4 v = Qg4[f];
      int row = f >> 4, c4 = f & 15;
      float* dst = &sQ[row][c4 * 4];
      dst[0] = v.x * 0.125f; dst[1] = v.y * 0.125f;
      dst[2] = v.z * 0.125f; dst[3] = v.w * 0.125f;
    }
  }

  float m0 = -3.0e38f, m1 = -3.0e38f, l0 = 0.f, l1 = 0.f;
  float4 o0 = make_float4(0.f, 0.f, 0.f, 0.f);
  float4 o1 = make_float4(0.f, 0.f, 0.f, 0.f);

  const int qg0 = q0 + 2 * qp, qg1 = qg0 + 1;

  for (int t = 0; t < ntiles; ++t) {
    const int k0 = t * 64;
    __syncthreads();
    {
      const float4* Kg4 = reinterpret_cast<const float4*>(Kb + (size_t)k0 * DHEAD);
      for (int it = 0; it < 4; ++it) {
        int f = tid + it * 256;
        int row = f & 63;
        int c4 = f >> 6;
        float4 v = Kg4[row * 16 + c4];
        sKT[c4 * 4 + 0][row] = v.x; sKT[c4 * 4 + 1][row] = v.y;
        sKT[c4 * 4 + 2][row] = v.z; sKT[c4 * 4 + 3][row] = v.w;
      }
      const float4* Vg4 = reinterpret_cast<const float4*>(Vb + (size_t)k0 * DHEAD);
      for (int it = 0; it < 4; ++it) {
        int f = tid + it * 256;
        int row = f >> 4, c4 = f & 15;
        *reinterpret_cast<float4*>(&sV[row][c4 * 4]) = Vg4[f];
      }
    }
    __syncthreads();

    float s00 = 0, s01 = 0, s02 = 0, s03 = 0;
    float s10 = 0, s11 = 0, s12 = 0, s13 = 0;
#pragma unroll
    for (int d4 = 0; d4 < 16; ++d4) {
      float4 qv0 = *reinterpret_cast<const float4*>(&sQ[2 * qp + 0][d4 * 4]);
      float4 qv1 = *reinterpret_cast<const float4*>(&sQ[2 * qp + 1][d4 * 4]);
#pragma unroll
      for (int e = 0; e < 4; ++e) {
        float4 kv = *reinterpret_cast<const float4*>(&sKT[d4 * 4 + e][kg * 4]);
        float qa = (e == 0) ? qv0.x : (e == 1) ? qv0.y : (e == 2) ? qv0.z : qv0.w;
        float qb = (e == 0) ? qv1.x : (e == 1) ? qv1.y : (e == 2) ? qv1.z : qv1.w;
        s00 += qa * kv.x; s01 += qa * kv.y; s02 += qa * kv.z; s03 += qa * kv.w;
        s10 += qb * kv.x; s11 += qb * kv.y; s12 += qb * kv.z; s13 += qb * kv.w;
      }
    }
    const int kb = k0 + kg * 4;
    if (kb + 0 > qg0) s00 = -3.0e38f;
    if (kb + 1 > qg0) s01 = -3.0e38f;
    if (kb + 2 > qg0) s02 = -3.0e38f;
    if (kb + 3 > qg0) s03 = -3.0e38f;
    if (kb + 0 > qg1) s10 = -3.0e38f;
    if (kb + 1 > qg1) s11 = -3.0e38f;
    if (kb + 2 > qg1) s12 = -3.0e38f;
    if (kb + 3 > qg1) s13 = -3.0e38f;

    float lm0 = fmaxf(fmaxf(s00, s01), fmaxf(s02, s03));
    float lm1 = fmaxf(fmaxf(s10, s11), fmaxf(s12, s13));
#pragma unroll
    for (int mm = 1; mm <= 8; mm <<= 1) {
      lm0 = fmaxf(lm0, __shfl_xor(lm0, mm, 64));
      lm1 = fmaxf(lm1, __shfl_xor(lm1, mm, 64));
    }
    float mn0 = fmaxf(m0, lm0), mn1 = fmaxf(m1, lm1);
    float sc0 = expf(m0 - mn0), sc1 = expf(m1 - mn1);
    float p00 = expf(s00 - mn0), p01 = expf(s01 - mn0);
    float p02 = expf(s02 - mn0), p03 = expf(s03 - mn0);
    float p10 = expf(s10 - mn1), p11 = expf(s11 - mn1);
    float p12 = expf(s12 - mn1), p13 = expf(s13 - mn1);
    float ls0 = p00 + p01 + p02 + p03;
    float ls1 = p10 + p11 + p12 + p13;
#pragma unroll
    for (int mm = 1; mm <= 8; mm <<= 1) {
      ls0 += __shfl_xor(ls0, mm, 64);
      ls1 += __shfl_xor(ls1, mm, 64);
    }
    l0 = l0 * sc0 + ls0;
    l1 = l1 * sc1 + ls1;
    o0.x *= sc0; o0.y *= sc0; o0.z *= sc0; o0.w *= sc0;
    o1.x *= sc1; o1.y *= sc1; o1.z *= sc1; o1.w *= sc1;
    m0 = mn0; m1 = mn1;

    *reinterpret_cast<float4*>(&sP[2 * qp + 0][kg * 4]) = make_float4(p00, p01, p02, p03);
    *reinterpret_cast<float4*>(&sP[2 * qp + 1][kg * 4]) = make_float4(p10, p11, p12, p13);
    __syncthreads();

#pragma unroll
    for (int k4 = 0; k4 < 16; ++k4) {
      float4 pa = *reinterpret_cast<const float4*>(&sP[2 * qp + 0][k4 * 4]);
      float4 pb = *reinterpret_cast<const float4*>(&sP[2 * qp + 1][k4 * 4]);
#pragma unroll
      for (int e = 0; e < 4; ++e) {
        float4 vv = *reinterpret_cast<const float4*>(&sV[k4 * 4 + e][kg * 4]);
        float w0 = (e == 0) ? pa.x : (e == 1) ? pa.y : (e == 2) ? pa.z : pa.w;
        float w1 = (e == 0) ? pb.x : (e == 1) ? pb.y : (e == 2) ? pb.z : pb.w;
        o0.x += w0 * vv.x; o0.y += w0 * vv.y; o0.z += w0 * vv.z; o0.w += w0 * vv.w;
        o1.x += w1 * vv.x; o1.y += w1 * vv.y; o1.z += w1 * vv.z; o1.w += w1 * vv.w;
      }
    }
  }

  const float inv0 = 1.f / l0, inv1 = 1.f / l1;
  float4 r0 = make_float4(o0.x * inv0, o0.y * inv0, o0.z * inv0, o0.w * inv0);
  float4 r1 = make_float4(o1.x * inv1, o1.y * inv1, o1.z * inv1, o1.w * inv1);
  *reinterpret_cast<float4*>(attn_out + (size_t)qg0 * DMODEL + h * DHEAD + kg * 4) = r0;
  *reinterpret_cast<float4*>(attn_out + (size_t)qg1 * DMODEL + h * DHEAD + kg * 4) = r1;
}

// ---------------- split-K projection: partial ----------------
__global__ __launch_bounds__(256) void proj_partial_kernel(
    const float* __restrict__ A, const float* __restrict__ Bm,
    float* __restrict__ part) {
  __shared__ float sA[64][68];
  __shared__ float sB[64][68];
  const int tid = threadIdx.x;
  const int tr = tid >> 4, tc = tid & 15;
  const int col0 = blockIdx.x * 64, row0 = blockIdx.y * 64;
  const int z = blockIdx.z;
  const int kbase = z * 256;
  float acc[4][4];
#pragma unroll
  for (int i = 0; i < 4; ++i)
#pragma unroll
    for (int j = 0; j < 4; ++j) acc[i][j] = 0.f;

  for (int kt = 0; kt < 4; ++kt) {
    const int k0 = kbase + kt * 64;
    __syncthreads();
    {
      const float4* Ag = reinterpret_cast<const float4*>(A + (size_t)row0 * DMODEL + k0);
#pragma unroll
      for (int it = 0; it < 4; ++it) {
        int f = tid + it * 256;
        int r = f >> 4, c4 = f & 15;
        *reinterpret_cast<float4*>(&sA[r][c4 * 4]) = Ag[r * 256 + c4];
      }
      const float4* Bg = reinterpret_cast<const float4*>(Bm + (size_t)k0 * DMODEL + col0);
#pragma unroll
      for (int it = 0; it < 4; ++it) {
        int f = tid + it * 256;
        int r = f >> 4, c4 = f & 15;
        *reinterpret_cast<float4*>(&sB[r][c4 * 4]) = Bg[r * 256 + c4];
      }
    }
    __syncthreads();
#pragma unroll 4
    for (int kk = 0; kk < 64; ++kk) {
      float a0 = sA[tr * 4 + 0][kk], a1 = sA[tr * 4 + 1][kk];
      float a2 = sA[tr * 4 + 2][kk], a3 = sA[tr * 4 + 3][kk];
      float4 b = *reinterpret_cast<const float4*>(&sB[kk][tc * 4]);
      acc[0][0] += a0 * b.x; acc[0][1] += a0 * b.y; acc[0][2] += a0 * b.z; acc[0][3] += a0 * b.w;
      acc[1][0] += a1 * b.x; acc[1][1] += a1 * b.y; acc[1][2] += a1 * b.z; acc[1][3] += a1 * b.w;
      acc[2][0] += a2 * b.x; acc[2][1] += a2 * b.y; acc[2][2] += a2 * b.z; acc[2][3] += a2 * b.w;
      acc[3][0] += a3 * b.x; acc[3][1] += a3 * b.y; acc[3][2] += a3 * b.z; acc[3][3] += a3 * b.w;
    }
  }

  float* dst = part + (size_t)z * (DMODEL * S_TOK);
#pragma unroll
  for (int i = 0; i < 4; ++i) {
    *reinterpret_cast<float4*>(dst + (size_t)(row0 + tr * 4 + i) * DMODEL + col0 + tc * 4) =
        make_float4(acc[i][0], acc[i][1], acc[i][2], acc[i][3]);
  }
}

// ---------------- projection combine: H = x + sum_z part[z] ----------------
__global__ __launch_bounds__(256) void proj_combine_kernel(
    const float* __restrict__ part, const float* __restrict__ x,
    float* __restrict__ H) {
  const int i = blockIdx.x * 256 + threadIdx.x;
  const float4* p4 = reinterpret_cast<const float4*>(part);
  float4 p0 = p4[i];
  float4 p1 = p4[i + 262144];
  float4 p2 = p4[i + 524288];
  float4 p3 = p4[i + 786432];
  float4 xv = reinterpret_cast<const float4*>(x)[i];
  reinterpret_cast<float4*>(H)[i] =
      make_float4(xv.x + p0.x + p1.x + p2.x + p3.x, xv.y + p0.y + p1.y + p2.y + p3.y,
                  xv.z + p0.z + p1.z + p2.z + p3.z, xv.w + p0.w + p1.w + p2.w + p3.w);
}

// ---------------- fallback proj (small ws) ----------------
__global__ __launch_bounds__(256) void proj_add_kernel(
    const float* __restrict__ A, const float* __restrict__ Bm,
    const float* __restrict__ x, float* __restrict__ H) {
  __shared__ float sA[64][65];
  __shared__ float sB[64][65];
  const int tid = threadIdx.x;
  const int tr = tid >> 4, tc = tid & 15;
  const int row0 = blockIdx.y * 64, col0 = blockIdx.x * 64;
  float acc[4][4];
#pragma unroll
  for (int i = 0; i < 4; ++i)
#pragma unroll
    for (int j = 0; j < 4; ++j) acc[i][j] = 0.f;
  for (int kt = 0; kt < 16; ++kt) {
#pragma unroll
    for (int e = tid; e < 4096; e += 256) {
      int r = e >> 6, c = e & 63;
      sA[r][c] = A[(size_t)(row0 + r) * DMODEL + (kt * 64 + c)];
      sB[r][c] = Bm[(size_t)(kt * 64 + r) * DMODEL + (col0 + c)];
    }
    __syncthreads();
#pragma unroll 4
    for (int kk = 0; kk < 64; ++kk) {
      float a0 = sA[tr * 4 + 0][kk], a1 = sA[tr * 4 + 1][kk];
      float a2 = sA[tr * 4 + 2][kk], a3 = sA[tr * 4 + 3][kk];
      float b0 = sB[kk][tc * 4 + 0], b1 = sB[kk][tc * 4 + 1];
      float b2 = sB[kk][tc * 4 + 2], b3 = sB[kk][tc * 4 + 3];
      acc[0][0] += a0 * b0; acc[0][1] += a0 * b1; acc[0][2] += a0 * b2; acc[0][3] += a0 * b3;
      acc[1][0] += a1 * b0; acc[1][1] += a1 * b1; acc[1][2] += a1 * b2; acc[1][3] += a1 * b3;
      acc[2][0] += a2 * b0; acc[2][1] += a2 * b1; acc[2][2] += a2 * b2; acc[2][3] += a2 * b3;
      acc[3][0] += a3 * b0; acc[3][1] += a3 * b1; acc[3][2] += a3 * b2; acc[3][3] += a3 * b3;
    }
    __syncthreads();
  }
#pragma unroll
  for (int i = 0; i < 4; ++i) {
    size_t ro = (size_t)(row0 + tr * 4 + i) * DMODEL + col0 + tc * 4;
#pragma unroll
    for (int j = 0; j < 4; ++j) H[ro + j] = x[ro + j] + acc[i][j];
  }
}

// ---------------- know token kernel (pass-2 over gate survivors only) ----------------
__global__ __launch_bounds__(256) void know_token_kernel(
    const float* __restrict__ h, const float* __restrict__ tau,
    const float* __restrict__ know_neurons,
    const int* __restrict__ idxk, const float* __restrict__ dk,
    float* __restrict__ out, float* __restrict__ loss_acc) {
  const int s = blockIdx.x;
  const int tid = threadIdx.x;
  const int lane = tid & 63, wave = tid >> 6;
  __shared__ __align__(16) float s_h[DMODEL];
  __shared__ float s_act[128];
  __shared__ float s_eg[128];
  __shared__ float s_w[128];
  __shared__ float s_wg[128];
  __shared__ float s_g[128];
  __shared__ int s_idx[128];
  __shared__ int s_klist[128];
  __shared__ int s_wcnt[2];
  __shared__ int s_kcnt;
  __shared__ float s_kth, s_gsum, s_strength;

  for (int i = tid; i < DMODEL; i += 256) s_h[i] = h[(size_t)s * DMODEL + i];
  if (tid < 128) s_idx[tid] = idxk[s * 128 + tid];
  __syncthreads();

  const float4* h4 = reinterpret_cast<const float4*>(s_h);
  for (int c = wave * 32; c < wave * 32 + 32; ++c) {
    const float4* row4 = reinterpret_cast<const float4*>(know_neurons + (size_t)s_idx[c] * DMODEL);
    float acc = 0.f;
#pragma unroll
    for (int k = 0; k < 4; ++k) {
      float4 rv = row4[lane + k * 64];
      float4 xv = h4[lane + k * 64];
      acc += rv.x * xv.x + rv.y * xv.y + rv.z * xv.z + rv.w * xv.w;
    }
    acc = wave_reduce_sum(acc);
    if (lane == 0) s_act[c] = acc;
  }
  __syncthreads();

  const float tv = tau[s];
  if (tid < 128) {
    float a = s_act[tid];
    float raw = a - tv;
    float gate = (raw > 0.f) ? raw : 1e-8f * __expf(raw);
    s_eg[tid] = __expf(gate) - 1.f;
  }
  __syncthreads();
  if (tid < 128) {
    float e = s_eg[tid];
    int rank = 0;
    for (int j = 0; j < 128; ++j) {
      float ej = s_eg[j];
      rank += ((ej > e) || (ej == e && j < tid)) ? 1 : 0;
    }
    if (rank == 63) s_kth = e;
  }
  __syncthreads();
  if (tid < 128) {
    float e = s_eg[tid];
    s_w[tid] = (e >= s_kth) ? e : 0.f;
  }
  __syncthreads();
  if (wave == 0) {
    float sum = wave_reduce_sum(s_w[lane] + s_w[lane + 64]);
    float mx = wave_reduce_max(fmaxf(s_eg[lane], s_eg[lane + 64]));
    if (lane == 0) { s_gsum = sum + 1e-8f; s_strength = tanhf(mx); }
  }
  // survivor compaction phase 1: per-wave counts
  if (tid < 128) {
    bool pred = s_w[tid] != 0.f;
    unsigned long long m = __ballot(pred);
    if (lane == 0) s_wcnt[wave] = __popcll(m);
  }
  __syncthreads();
  if (tid < 128) {
    float g = s_w[tid] / s_gsum * s_strength;
    s_g[tid] = g;
    s_wg[tid] = s_act[tid] * g;
    bool pred = s_w[tid] != 0.f;
    unsigned long long m = __ballot(pred);
    int base = (wave == 1) ? s_wcnt[0] : 0;
    int pos = base + __popcll(m & ((1ull << lane) - 1ull));
    if (pred) s_klist[pos] = tid;
    if (tid == 0) s_kcnt = s_wcnt[0] + s_wcnt[1];
  }
  __syncthreads();
  if (wave == 0) {
    float pl = s_g[lane] * dk[s * 128 + lane] + s_g[lane + 64] * dk[s * 128 + lane + 64];
    pl = wave_reduce_sum(pl);
    if (lane == 0) atomicAdd(loss_acc, pl * (1.f / 131072.f));
  }

  const int d0 = tid * 4;
  const int kc = s_kcnt;
  float a0 = 0, a1 = 0, a2 = 0, a3 = 0;
  for (int j = 0; j < kc; ++j) {
    const int c = s_klist[j];
    const float4 r = *reinterpret_cast<const float4*>(know_neurons + (size_t)s_idx[c] * DMODEL + d0);
    const float wv = s_wg[c];
    a0 += wv * r.x; a1 += wv * r.y; a2 += wv * r.z; a3 += wv * r.w;
  }
  float h0 = s_h[d0 + 0], h1 = s_h[d0 + 1], h2 = s_h[d0 + 2], h3 = s_h[d0 + 3];
  *reinterpret_cast<float4*>(out + (size_t)s * DMODEL + d0) =
      make_float4(h0 + a0, h1 + a1, h2 + a2, h3 + a3);
}

extern "C" void kernel_launch(void* const* d_in, const int* in_sizes, int n_in,
                              void* d_out, int out_size, void* d_ws, size_t ws_size,
                              hipStream_t stream) {
  const float* x = (const float*)d_in[0];
  const float* qk_pos = (const float*)d_in[1];
  const float* v_pos = (const float*)d_in[2];
  const float* know_pos = (const float*)d_in[3];
  const float* tau_q = (const float*)d_in[4];
  const float* tau_k = (const float*)d_in[5];
  const float* tau_v = (const float*)d_in[6];
  const float* tau_know = (const float*)d_in[7];
  const float* qk_neurons = (const float*)d_in[8];
  const float* v_neurons = (const float*)d_in[9];
  const float* know_neurons = (const float*)d_in[10];
  const float* npos_qk = (const float*)d_in[11];
  const float* npos_v = (const float*)d_in[12];
  const float* npos_know = (const float*)d_in[13];
  const float* expand_O = (const float*)d_in[14];
  float* out = (float*)d_out;
  float* loss_acc = out + (size_t)S_TOK * DMODEL;

  char* w = (char*)d_ws;
  int* idx_qk = (int*)(w + 0);
  float* dist_qk = (float*)(w + 262144);
  int* idx_v = (int*)(w + 524288);
  float* dist_v = (float*)(w + 786432);
  int* idx_know = (int*)(w + 1048576);
  float* dist_know = (float*)(w + 1572864);
  float* Qb = (float*)(w + 2097152);
  float* Kb = (float*)(w + 6291456);
  float* Vb = (float*)(w + 10485760);
  float* attnbuf = (float*)(w + 14680064);
  float* hbuf = (float*)(w + 18874368);
  float* Rbuf = (float*)(w + 23068672);  // 16 MB scratch: selects -> attn partials -> proj partials

  hipMemsetAsync(loss_acc, 0, sizeof(float), stream);

  const bool big_ws = ws_size >= (size_t)23068672 + 16777216;
  if (big_ws) {
    rgemm_kernel<<<dim3(32, 16), 256, 0, stream>>>(qk_pos, npos_qk, Rbuf, 0, 4096);
    select2_kernel<4096, 64><<<1024, 256, 0, stream>>>(Rbuf, qk_pos, npos_qk, 0, idx_qk, dist_qk);
    rgemm_kernel<<<dim3(32, 16), 256, 0, stream>>>(v_pos, npos_v, Rbuf, 0, 4096);
    select2_kernel<4096, 64><<<1024, 256, 0, stream>>>(Rbuf, v_pos, npos_v, 0, idx_v, dist_v);
    rgemm_kernel<<<dim3(64, 8), 256, 0, stream>>>(know_pos, npos_know, Rbuf, 0, 8192);
    select2_kernel<8192, 128><<<512, 256, 0, stream>>>(Rbuf, know_pos, npos_know, 0, idx_know, dist_know);
    rgemm_kernel<<<dim3(64, 8), 256, 0, stream>>>(know_pos, npos_know, Rbuf, 512, 8192);
    select2_kernel<8192, 128><<<512, 256, 0, stream>>>(Rbuf, know_pos, npos_know, 512, idx_know, dist_know);
  } else {
    select_topk_fused_kernel<4096, 64><<<S_TOK, 256, 0, stream>>>(qk_pos, npos_qk, idx_qk, dist_qk);
    select_topk_fused_kernel<4096, 64><<<S_TOK, 256, 0, stream>>>(v_pos, npos_v, idx_v, dist_v);
    select_topk_fused_kernel<8192, 128><<<S_TOK, 256, 0, stream>>>(know_pos, npos_know, idx_know, dist_know);
  }

  attn_token_kernel<<<S_TOK, 256, 0, stream>>>(x, tau_q, tau_k, tau_v, qk_neurons, v_neurons,
                                               idx_qk, dist_qk, idx_v, dist_v, Qb, Kb, Vb, loss_acc);

  if (big_ws) {
    attention_partial_kernel<<<1280, 256, 0, stream>>>(Qb, Kb, Vb, Rbuf);
    attention_combine_kernel<<<512, 256, 0, stream>>>(Rbuf, attnbuf);
    proj_partial_kernel<<<dim3(16, 16, 4), 256, 0, stream>>>(attnbuf, expand_O, Rbuf);
    proj_combine_kernel<<<1024, 256, 0, stream>>>(Rbuf, x, hbuf);
  } else {
    attention_kernel<<<512, 256, 0, stream>>>(Qb, Kb, Vb, attnbuf);
    proj_add_kernel<<<dim3(16, 16), 256, 0, stream>>>(attnbuf, expand_O, x, hbuf);
  }

  know_token_kernel<<<S_TOK, 256, 0, stream>>>(hbuf, tau_know, know_neurons, idx_know, dist_know,
                                               out, loss_acc);
}

// Round 12
// 347.141 us; speedup vs baseline: 1.1284x; 1.0476x over previous
//
#include <hip/hip_runtime.h>
#include <math.h>

#define S_TOK 1024
#define DMODEL 1024
#define PDIM 32
#define NHEADS 16
#define DHEAD 64

__device__ __forceinline__ float wave_reduce_sum(float v) {
#pragma unroll
  for (int m = 32; m >= 1; m >>= 1) v += __shfl_xor(v, m, 64);
  return v;
}
__device__ __forceinline__ float wave_reduce_max(float v) {
#pragma unroll
  for (int m = 32; m >= 1; m >>= 1) v = fmaxf(v, __shfl_xor(v, m, 64));
  return v;
}
__device__ __forceinline__ float wave_reduce_min(float v) {
#pragma unroll
  for (int m = 32; m >= 1; m >>= 1) v = fminf(v, __shfl_xor(v, m, 64));
  return v;
}

#define NBINS 4096
#define CAND_MAX 512

// ---------------- r-GEMM: R[s, n] = ||n||^2 - 2 * p_s . n ----------------
__global__ __launch_bounds__(256) void rgemm_kernel(
    const float* __restrict__ pos, const float* __restrict__ npos,
    float* __restrict__ R, int s0, int N) {
  __shared__ float sAT[32][68];
  __shared__ float sBT[32][2][68];
  __shared__ float s_nrm[128];
  const int tid = threadIdx.x;
  const int n0 = blockIdx.x * 128;
  const int t0 = blockIdx.y * 64;

  {
    const float4* g = reinterpret_cast<const float4*>(pos + (size_t)(s0 + t0) * PDIM);
#pragma unroll
    for (int i = 0; i < 2; ++i) {
      int f = tid + i * 256;
      float4 v = g[f];
      int t = f >> 3, ks = (f & 7) * 4;
      sAT[ks + 0][t] = v.x; sAT[ks + 1][t] = v.y;
      sAT[ks + 2][t] = v.z; sAT[ks + 3][t] = v.w;
    }
    const float4* gb = reinterpret_cast<const float4*>(npos + (size_t)n0 * PDIM);
#pragma unroll
    for (int i = 0; i < 4; ++i) {
      int f = tid + i * 256;
      float4 v = gb[f];
      int n = f >> 3, ks = (f & 7) * 4;
      int hh = n >> 6, m = n & 63;
      sBT[ks + 0][hh][m] = v.x; sBT[ks + 1][hh][m] = v.y;
      sBT[ks + 2][hh][m] = v.z; sBT[ks + 3][hh][m] = v.w;
    }
  }
  __syncthreads();
  if (tid < 128) {
    int hh = tid >> 6, m = tid & 63;
    float acc = 0.f;
#pragma unroll
    for (int k = 0; k < 32; ++k) { float b = sBT[k][hh][m]; acc += b * b; }
    s_nrm[tid] = acc;
  }
  __syncthreads();

  const int tt = tid >> 4, nn = tid & 15;
  float acc[4][8];
#pragma unroll
  for (int i = 0; i < 4; ++i)
#pragma unroll
    for (int j = 0; j < 8; ++j) acc[i][j] = 0.f;

#pragma unroll 8
  for (int k = 0; k < 32; ++k) {
    const float4 a = *reinterpret_cast<const float4*>(&sAT[k][tt * 4]);
    const float4 b0 = *reinterpret_cast<const float4*>(&sBT[k][0][nn * 4]);
    const float4 b1 = *reinterpret_cast<const float4*>(&sBT[k][1][nn * 4]);
    const float av[4] = {a.x, a.y, a.z, a.w};
#pragma unroll
    for (int t = 0; t < 4; ++t) {
      acc[t][0] += av[t] * b0.x; acc[t][1] += av[t] * b0.y;
      acc[t][2] += av[t] * b0.z; acc[t][3] += av[t] * b0.w;
      acc[t][4] += av[t] * b1.x; acc[t][5] += av[t] * b1.y;
      acc[t][6] += av[t] * b1.z; acc[t][7] += av[t] * b1.w;
    }
  }

  const float n00 = s_nrm[nn * 4 + 0], n01 = s_nrm[nn * 4 + 1];
  const float n02 = s_nrm[nn * 4 + 2], n03 = s_nrm[nn * 4 + 3];
  const float n10 = s_nrm[64 + nn * 4 + 0], n11 = s_nrm[64 + nn * 4 + 1];
  const float n12 = s_nrm[64 + nn * 4 + 2], n13 = s_nrm[64 + nn * 4 + 3];
#pragma unroll
  for (int t = 0; t < 4; ++t) {
    const size_t ro = (size_t)(t0 + tt * 4 + t) * N + n0;
    float4 r0 = make_float4(fmaf(-2.f, acc[t][0], n00), fmaf(-2.f, acc[t][1], n01),
                            fmaf(-2.f, acc[t][2], n02), fmaf(-2.f, acc[t][3], n03));
    float4 r1 = make_float4(fmaf(-2.f, acc[t][4], n10), fmaf(-2.f, acc[t][5], n11),
                            fmaf(-2.f, acc[t][6], n12), fmaf(-2.f, acc[t][7], n13));
    *reinterpret_cast<float4*>(R + ro + nn * 4) = r0;
    *reinterpret_cast<float4*>(R + ro + 64 + nn * 4) = r1;
  }
}

// ---------------- slim select on precomputed R row ----------------
template <int N, int K>
__global__ __launch_bounds__(256) void select2_kernel(
    const float* __restrict__ R, const float* __restrict__ pos,
    const float* __restrict__ npos, int s0,
    int* __restrict__ out_idx, float* __restrict__ out_dist) {
  const int bid = blockIdx.x;
  const int s = s0 + bid;
  const int tid = threadIdx.x;
  const int lane = tid & 63;
  const int wave = tid >> 6;

  __shared__ float s_dist[N];
  __shared__ unsigned s_hist[NBINS];
  __shared__ unsigned s_part[256];
  __shared__ float4 s_p4[8];
  __shared__ float s_red[16];
  __shared__ float s_lo, s_scale;
  __shared__ int s_B, s_need, s_cnt, s_ccnt;
  __shared__ int s_selidx[K];
  __shared__ float s_seldist[K];
  __shared__ int s_cidx[CAND_MAX];
  __shared__ float s_cdist[CAND_MAX];

  if (tid < 8) s_p4[tid] = reinterpret_cast<const float4*>(pos + (size_t)s * PDIM)[tid];
  for (int j = tid; j < K; j += 256) s_selidx[j] = 0;
  for (int b = tid; b < NBINS; b += 256) s_hist[b] = 0u;
  __syncthreads();

  float lmin = 3.0e38f, lmax = -3.0e38f;
  const float* row = R + (size_t)bid * N;
#pragma unroll 4
  for (int i = 0; i < N / 256; ++i) {
    float v = row[tid + i * 256];
    s_dist[tid + i * 256] = v;
    lmin = fminf(lmin, v);
    lmax = fmaxf(lmax, v);
  }
  lmin = wave_reduce_min(lmin);
  lmax = wave_reduce_max(lmax);
  if (lane == 0) { s_red[wave] = lmin; s_red[8 + wave] = lmax; }
  __syncthreads();
  if (tid == 0) {
    float lo = s_red[0], hi = s_red[8];
    for (int w2 = 1; w2 < 4; ++w2) {
      lo = fminf(lo, s_red[w2]);
      hi = fmaxf(hi, s_red[8 + w2]);
    }
    s_lo = lo;
    s_scale = (float)NBINS / fmaxf(hi - lo, 1e-30f);
  }
  __syncthreads();

  const float lo = s_lo, scale = s_scale;
  for (int n = tid; n < N; n += 256) {
    int b = min(NBINS - 1, (int)((s_dist[n] - lo) * scale));
    atomicAdd(&s_hist[b], 1u);
  }
  __syncthreads();

  unsigned psum = 0;
#pragma unroll 4
  for (int b = tid * 16; b < tid * 16 + 16; ++b) psum += s_hist[b];
  s_part[tid] = psum;
  __syncthreads();
  if (tid == 0) {
    unsigned cum = 0;
    int c = 0;
    for (; c < 256; ++c) {
      unsigned pc = s_part[c];
      if (cum + pc >= (unsigned)K) break;
      cum += pc;
    }
    int b = c * 16;
    for (;; ++b) {
      unsigned cb = s_hist[b];
      if (cum + cb >= (unsigned)K) break;
      cum += cb;
    }
    s_B = b;
    s_need = K - (int)cum;
    s_cnt = 0;
    s_ccnt = 0;
  }
  __syncthreads();

  const int B = s_B;
  for (int n = tid; n < N; n += 256) {
    float d = s_dist[n];
    int b = min(NBINS - 1, (int)((d - lo) * scale));
    if (b < B) {
      int p = atomicAdd(&s_cnt, 1);
      s_selidx[p] = n;
    } else if (b == B) {
      int e = atomicAdd(&s_ccnt, 1);
      if (e < CAND_MAX) { s_cidx[e] = n; s_cdist[e] = d; }
    }
  }
  __syncthreads();

  const int M = s_ccnt < CAND_MAX ? s_ccnt : CAND_MAX;
  const int need = s_need;
  const int base = s_cnt;
  for (int i = tid; i < M; i += 256) {
    float di = s_cdist[i];
    int idxi = s_cidx[i];
    int rank = 0;
    for (int j = 0; j < M; ++j) {
      float dj = s_cdist[j];
      rank += (dj < di || (dj == di && s_cidx[j] < idxi)) ? 1 : 0;
    }
    if (rank < need) s_selidx[base + rank] = idxi;
  }
  __syncthreads();

  {
    const int g = tid >> 3, sl = tid & 7;
    const float4 pv = s_p4[sl];
    for (int j = g; j < K; j += 32) {
      const float4 nv =
          *reinterpret_cast<const float4*>(npos + (size_t)s_selidx[j] * PDIM + sl * 4);
      float dx = pv.x - nv.x, dy = pv.y - nv.y, dz = pv.z - nv.z, dw = pv.w - nv.w;
      float d = dx * dx + dy * dy + dz * dz + dw * dw;
      d += __shfl_xor(d, 1, 64);
      d += __shfl_xor(d, 2, 64);
      d += __shfl_xor(d, 4, 64);
      if (sl == 0) s_seldist[j] = d;
    }
  }
  __syncthreads();
  for (int j = tid; j < K; j += 256) {
    out_idx[(size_t)s * K + j] = s_selidx[j];
    out_dist[(size_t)s * K + j] = s_seldist[j];
  }
}

// ---------------- fallback: fused distance+select ----------------
template <int N, int K>
__global__ __launch_bounds__(256) void select_topk_fused_kernel(
    const float* __restrict__ pos, const float* __restrict__ npos,
    int* __restrict__ out_idx, float* __restrict__ out_dist) {
  const int s = blockIdx.x;
  const int tid = threadIdx.x;
  const int lane = tid & 63;
  const int wave = tid >> 6;
  const int sl = lane & 7;
  const int rw = lane >> 3;

  __shared__ float s_dist[N];
  __shared__ unsigned s_hist[NBINS];
  __shared__ unsigned s_part[256];
  __shared__ float4 s_p4[8];
  __shared__ float s_red[16];
  __shared__ float s_lo, s_scale;
  __shared__ int s_B, s_need;
  __shared__ int s_cnt, s_ccnt;
  __shared__ int s_selidx[K];
  __shared__ float s_seldist[K];
  __shared__ int s_cidx[CAND_MAX];
  __shared__ float s_cdist[CAND_MAX];

  if (tid < 8) s_p4[tid] = reinterpret_cast<const float4*>(pos + (size_t)s * PDIM)[tid];
  for (int j = tid; j < K; j += 256) { s_selidx[j] = 0; s_seldist[j] = 0.f; }
  for (int b = tid; b < NBINS; b += 256) s_hist[b] = 0u;
  __syncthreads();

  const float4 pv = s_p4[sl];
  float lmin = 3.0e38f, lmax = -3.0e38f;
  const int rows_per_wave = N / 4;
  const int rbase = wave * rows_per_wave;
  for (int it = 0; it < rows_per_wave; it += 16) {
    const int ra = rbase + it + rw;
    const int rb = ra + 8;
    const float4 na = *reinterpret_cast<const float4*>(npos + (size_t)ra * PDIM + sl * 4);
    const float4 nb = *reinterpret_cast<const float4*>(npos + (size_t)rb * PDIM + sl * 4);
    float dax = pv.x - na.x, day = pv.y - na.y, daz = pv.z - na.z, daw = pv.w - na.w;
    float dbx = pv.x - nb.x, dby = pv.y - nb.y, dbz = pv.z - nb.z, dbw = pv.w - nb.w;
    float da = dax * dax + day * day + daz * daz + daw * daw;
    float db = dbx * dbx + dby * dby + dbz * dbz + dbw * dbw;
    da += __shfl_xor(da, 1, 64); da += __shfl_xor(da, 2, 64); da += __shfl_xor(da, 4, 64);
    db += __shfl_xor(db, 1, 64); db += __shfl_xor(db, 2, 64); db += __shfl_xor(db, 4, 64);
    lmin = fminf(lmin, fminf(da, db));
    lmax = fmaxf(lmax, fmaxf(da, db));
    if (sl == 0) { s_dist[ra] = da; s_dist[rb] = db; }
  }
  lmin = wave_reduce_min(lmin);
  lmax = wave_reduce_max(lmax);
  if (lane == 0) { s_red[wave] = lmin; s_red[8 + wave] = lmax; }
  __syncthreads();
  if (tid == 0) {
    float lo = s_red[0], hi = s_red[8];
    for (int w2 = 1; w2 < 4; ++w2) {
      lo = fminf(lo, s_red[w2]);
      hi = fmaxf(hi, s_red[8 + w2]);
    }
    s_lo = lo;
    s_scale = (float)NBINS / fmaxf(hi - lo, 1e-30f);
  }
  __syncthreads();

  const float lo = s_lo, scale = s_scale;
  for (int n = tid; n < N; n += 256) {
    int b = min(NBINS - 1, (int)((s_dist[n] - lo) * scale));
    atomicAdd(&s_hist[b], 1u);
  }
  __syncthreads();

  unsigned psum = 0;
#pragma unroll 4
  for (int b = tid * 16; b < tid * 16 + 16; ++b) psum += s_hist[b];
  s_part[tid] = psum;
  __syncthreads();
  if (tid == 0) {
    unsigned cum = 0;
    int c = 0;
    for (; c < 256; ++c) {
      unsigned pc = s_part[c];
      if (cum + pc >= (unsigned)K) break;
      cum += pc;
    }
    int b = c * 16;
    for (;; ++b) {
      unsigned cb = s_hist[b];
      if (cum + cb >= (unsigned)K) break;
      cum += cb;
    }
    s_B = b;
    s_need = K - (int)cum;
    s_cnt = 0;
    s_ccnt = 0;
  }
  __syncthreads();

  const int B = s_B;
  for (int n = tid; n < N; n += 256) {
    float d = s_dist[n];
    int b = min(NBINS - 1, (int)((d - lo) * scale));
    if (b < B) {
      int p = atomicAdd(&s_cnt, 1);
      s_selidx[p] = n;
      s_seldist[p] = d;
    } else if (b == B) {
      int e = atomicAdd(&s_ccnt, 1);
      if (e < CAND_MAX) { s_cidx[e] = n; s_cdist[e] = d; }
    }
  }
  __syncthreads();

  const int M = s_ccnt < CAND_MAX ? s_ccnt : CAND_MAX;
  const int need = s_need;
  const int base = s_cnt;
  for (int i = tid; i < M; i += 256) {
    unsigned ki = __float_as_uint(s_cdist[i]);
    int idxi = s_cidx[i];
    int rank = 0;
    for (int j = 0; j < M; ++j) {
      unsigned kj = __float_as_uint(s_cdist[j]);
      rank += (kj < ki || (kj == ki && s_cidx[j] < idxi)) ? 1 : 0;
    }
    if (rank < need) {
      s_selidx[base + rank] = idxi;
      s_seldist[base + rank] = s_cdist[i];
    }
  }
  __syncthreads();

  for (int j = tid; j < K; j += 256) {
    out_idx[(size_t)s * K + j] = s_selidx[j];
    out_dist[(size_t)s * K + j] = s_seldist[j];
  }
}

// ---------------- attn token kernel (pass-2 over gate survivors only) ----------------
__global__ __launch_bounds__(256) void attn_token_kernel(
    const float* __restrict__ x,
    const float* __restrict__ tau_q, const float* __restrict__ tau_k,
    const float* __restrict__ tau_v,
    const float* __restrict__ qk_neurons, const float* __restrict__ v_neurons,
    const int* __restrict__ idx_qk, const float* __restrict__ d_qk,
    const int* __restrict__ idx_v, const float* __restrict__ d_v,
    float* __restrict__ Qh, float* __restrict__ Kh, float* __restrict__ Vh,
    float* __restrict__ loss_acc) {
  const int s = blockIdx.x;
  const int tid = threadIdx.x;
  const int lane = tid & 63;
  const int wave = tid >> 6;
  __shared__ __align__(16) float s_x[DMODEL];
  __shared__ float s_act_qk[64], s_act_v[64];
  __shared__ float s_wq[64], s_wk[64], s_wv[64];
  __shared__ float s_gq[64], s_gv[64];
  __shared__ int s_iqk[64], s_iv[64];
  __shared__ int s_qklist[64], s_vlist[64];
  __shared__ int s_qkcnt, s_vcnt;

  for (int i = tid; i < DMODEL; i += 256) s_x[i] = x[(size_t)s * DMODEL + i];
  if (tid < 64) {
    s_iqk[tid] = idx_qk[s * 64 + tid];
    s_iv[tid] = idx_v[s * 64 + tid];
  }
  __syncthreads();

  const float4* x4 = reinterpret_cast<const float4*>(s_x);
  for (int c = wave * 16; c < wave * 16 + 16; ++c) {
    const float4* row4 = reinterpret_cast<const float4*>(qk_neurons + (size_t)s_iqk[c] * DMODEL);
    float acc = 0.f;
#pragma unroll
    for (int k = 0; k < 4; ++k) {
      float4 rv = row4[lane + k * 64];
      float4 xv = x4[lane + k * 64];
      acc += rv.x * xv.x + rv.y * xv.y + rv.z * xv.z + rv.w * xv.w;
    }
    acc = wave_reduce_sum(acc);
    if (lane == 0) s_act_qk[c] = acc;
  }
  for (int c = wave * 16; c < wave * 16 + 16; ++c) {
    const float4* row4 = reinterpret_cast<const float4*>(v_neurons + (size_t)s_iv[c] * DMODEL);
    float acc = 0.f;
#pragma unroll
    for (int k = 0; k < 4; ++k) {
      float4 rv = row4[lane + k * 64];
      float4 xv = x4[lane + k * 64];
      acc += rv.x * xv.x + rv.y * xv.y + rv.z * xv.z + rv.w * xv.w;
    }
    acc = wave_reduce_sum(acc);
    if (lane == 0) s_act_v[c] = acc;
  }
  __syncthreads();

  if (wave < 3) {
    const float a = (wave == 2) ? s_act_v[lane] : s_act_qk[lane];
    const float tau = (wave == 0) ? tau_q[s] : (wave == 1) ? tau_k[s] : tau_v[s];
    float raw = a - tau;
    float gate = (raw > 0.f) ? raw : 1e-8f * __expf(raw);
    float eg = __expf(gate) - 1.f;
    int rank = 0;
    for (int j = 0; j < 64; ++j) {
      float vj = __shfl(eg, j, 64);
      rank += ((vj > eg) || (vj == eg && j < lane)) ? 1 : 0;
    }
    unsigned long long bm = __ballot(rank == 31);
    int srcl = __ffsll(bm) - 1;
    float kthv = __shfl(eg, srcl, 64);
    float w = (eg >= kthv) ? eg : 0.f;
    float gsum = wave_reduce_sum(w) + 1e-8f;
    float strength = tanhf(wave_reduce_max(eg));
    float g = w / gsum * strength;
    if (wave == 0) { s_wq[lane] = a * g; s_gq[lane] = g; }
    else if (wave == 1) { s_wk[lane] = a * g; }
    else { s_wv[lane] = a * g; s_gv[lane] = g; }
  }
  __syncthreads();

  // survivor compaction (deterministic, index-ordered)
  if (wave == 0) {
    bool pred = (s_wq[lane] != 0.f) || (s_wk[lane] != 0.f);
    unsigned long long m = __ballot(pred);
    int pos = __popcll(m & ((1ull << lane) - 1ull));
    if (pred) s_qklist[pos] = lane;
    if (lane == 0) s_qkcnt = __popcll(m);
  } else if (wave == 1) {
    bool pred = (s_wv[lane] != 0.f);
    unsigned long long m = __ballot(pred);
    int pos = __popcll(m & ((1ull << lane) - 1ull));
    if (pred) s_vlist[pos] = lane;
    if (lane == 0) s_vcnt = __popcll(m);
  } else if (wave == 2) {
    float pl = s_gq[lane] * d_qk[s * 64 + lane] + s_gv[lane] * d_v[s * 64 + lane];
    pl = wave_reduce_sum(pl);
    if (lane == 0) atomicAdd(loss_acc, pl * (1.f / 65536.f));
  }
  __syncthreads();

  // pass 2 over survivors only (skipped rows have exactly-zero weight)
  const int d0 = tid * 4;
  const int nqk = s_qkcnt, nv = s_vcnt;
  float aq0 = 0, aq1 = 0, aq2 = 0, aq3 = 0;
  float ak0 = 0, ak1 = 0, ak2 = 0, ak3 = 0;
  float av0 = 0, av1 = 0, av2 = 0, av3 = 0;
  for (int j = 0; j < nqk; ++j) {
    const int c = s_qklist[j];
    const float4 r = *reinterpret_cast<const float4*>(qk_neurons + (size_t)s_iqk[c] * DMODEL + d0);
    const float wq = s_wq[c], wk = s_wk[c];
    aq0 += wq * r.x; aq1 += wq * r.y; aq2 += wq * r.z; aq3 += wq * r.w;
    ak0 += wk * r.x; ak1 += wk * r.y; ak2 += wk * r.z; ak3 += wk * r.w;
  }
  for (int j = 0; j < nv; ++j) {
    const int c = s_vlist[j];
    const float4 r = *reinterpret_cast<const float4*>(v_neurons + (size_t)s_iv[c] * DMODEL + d0);
    const float wv = s_wv[c];
    av0 += wv * r.x; av1 += wv * r.y; av2 += wv * r.z; av3 += wv * r.w;
  }
  const int hh = d0 >> 6;
  const int dh = d0 & 63;
  const size_t base = ((size_t)hh * S_TOK + s) * DHEAD + dh;
  *reinterpret_cast<float4*>(Qh + base) = make_float4(aq0, aq1, aq2, aq3);
  *reinterpret_cast<float4*>(Kh + base) = make_float4(ak0, ak1, ak2, ak3);
  *reinterpret_cast<float4*>(Vh + base) = make_float4(av0, av1, av2, av3);
}

// ---------------- split-K attention: partial kernel (K/V time-share one LDS buffer) ----------
// LDS: sQ 8.7K + sKV 17.4K + sP 8.7K = 34.8 KB -> 4 blocks/CU. 4 barriers/tile.
// block -> (h, qt, chunk of 256 keys); slot: o[32][64], m[32], l[32] = 2112 floats.
__global__ __launch_bounds__(256) void attention_partial_kernel(
    const float* __restrict__ Q, const float* __restrict__ K,
    const float* __restrict__ V, float* __restrict__ part) {
  __shared__ float sQ[32][68];
  __shared__ float sKV[64][68];   // K transposed [dim][key] in score phase; V [key][dim] in PV phase
  __shared__ float sP[32][68];

  const int tid = threadIdx.x;
  const int bid = blockIdx.x;
  const int sw = (bid & 7) * 160 + (bid >> 3);  // XCD-contiguous
  const int h = sw / 80;
  const int r80 = sw % 80;
  int qt, c;
  if (r80 < 8) { qt = r80; c = 0; }
  else if (r80 < 24) { qt = 8 + ((r80 - 8) >> 1); c = (r80 - 8) & 1; }
  else if (r80 < 48) { qt = 16 + (r80 - 24) / 3; c = (r80 - 24) % 3; }
  else { qt = 24 + ((r80 - 48) >> 2); c = (r80 - 48) & 3; }
  const int q0 = qt * 32;
  const int kstart = c * 256;
  const int kend = min((qt + 1) * 32, kstart + 256);
  const int ntiles = (kend - kstart + 63) >> 6;
  const int g = qt >> 3;
  const int sbase = qt + 4 * g * (g - 1) + (qt - 8 * g) * g;
  float* slot = part + ((size_t)h * 80 + sbase + c) * 2112;

  const int qp = tid >> 4;
  const int kg = tid & 15;

  const float* Qb = Q + (size_t)h * S_TOK * DHEAD;
  const float* Kb = K + (size_t)h * S_TOK * DHEAD;
  const float* Vb = V + (size_t)h * S_TOK * DHEAD;

  {
    const float4* Qg4 = reinterpret_cast<const float4*>(Qb + (size_t)q0 * DHEAD);
    for (int f = tid; f < 512; f += 256) {
      float4 v = Qg4[f];
      int row = f >> 4, c4 = f & 15;
      float* dst = &sQ[row][c4 * 4];
      dst[0] = v.x * 0.125f; dst[1] = v.y * 0.125f;
      dst[2] = v.z * 0.125f; dst[3] = v.w * 0.125f;
    }
  }

  float m0 = -3.0e38f, m1 = -3.0e38f, l0 = 0.f, l1 = 0.f;
  float4 o0 = make_float4(0.f, 0.f, 0.f, 0.f);
  float4 o1 = make_float4(0.f, 0.f, 0.f, 0.f);

  const int qg0 = q0 + 2 * qp, qg1 = qg0 + 1;

  for (int t = 0; t < ntiles; ++t) {
    const int k0 = kstart + t * 64;
    __syncthreads();  // prev PV readers done with sKV/sP (also covers Q staging at t=0)
    // stage K transposed into sKV
    {
      const float4* Kg4 = reinterpret_cast<const float4*>(Kb + (size_t)k0 * DHEAD);
      for (int it = 0; it < 4; ++it) {
        int f = tid + it * 256;
        int row = f & 63;
        int c4 = f >> 6;
        float4 v = Kg4[row * 16 + c4];
        sKV[c4 * 4 + 0][row] = v.x; sKV[c4 * 4 + 1][row] = v.y;
        sKV[c4 * 4 + 2][row] = v.z; sKV[c4 * 4 + 3][row] = v.w;
      }
    }
    __syncthreads();

    // ---- scores: rows {2qp, 2qp+1} x keys {4kg..4kg+3} ----
    float s00 = 0, s01 = 0, s02 = 0, s03 = 0;
    float s10 = 0, s11 = 0, s12 = 0, s13 = 0;
#pragma unroll
    for (int d4 = 0; d4 < 16; ++d4) {
      float4 qv0 = *reinterpret_cast<const float4*>(&sQ[2 * qp + 0][d4 * 4]);
      float4 qv1 = *reinterpret_cast<const float4*>(&sQ[2 * qp + 1][d4 * 4]);
#pragma unroll
      for (int e = 0; e < 4; ++e) {
        float4 kv = *reinterpret_cast<const float4*>(&sKV[d4 * 4 + e][kg * 4]);
        float qa = (e == 0) ? qv0.x : (e == 1) ? qv0.y : (e == 2) ? qv0.z : qv0.w;
        float qb = (e == 0) ? qv1.x : (e == 1) ? qv1.y : (e == 2) ? qv1.z : qv1.w;
        s00 += qa * kv.x; s01 += qa * kv.y; s02 += qa * kv.z; s03 += qa * kv.w;
        s10 += qb * kv.x; s11 += qb * kv.y; s12 += qb * kv.z; s13 += qb * kv.w;
      }
    }
    // causal mask
    const int kb = k0 + kg * 4;
    if (kb + 0 > qg0) s00 = -3.0e38f;
    if (kb + 1 > qg0) s01 = -3.0e38f;
    if (kb + 2 > qg0) s02 = -3.0e38f;
    if (kb + 3 > qg0) s03 = -3.0e38f;
    if (kb + 0 > qg1) s10 = -3.0e38f;
    if (kb + 1 > qg1) s11 = -3.0e38f;
    if (kb + 2 > qg1) s12 = -3.0e38f;
    if (kb + 3 > qg1) s13 = -3.0e38f;

    // online softmax: row stats across the 16-lane group sharing qp
    float lm0 = fmaxf(fmaxf(s00, s01), fmaxf(s02, s03));
    float lm1 = fmaxf(fmaxf(s10, s11), fmaxf(s12, s13));
#pragma unroll
    for (int mm = 1; mm <= 8; mm <<= 1) {
      lm0 = fmaxf(lm0, __shfl_xor(lm0, mm, 64));
      lm1 = fmaxf(lm1, __shfl_xor(lm1, mm, 64));
    }
    float mn0 = fmaxf(m0, lm0), mn1 = fmaxf(m1, lm1);
    float sc0 = __expf(m0 - mn0), sc1 = __expf(m1 - mn1);
    float p00 = __expf(s00 - mn0), p01 = __expf(s01 - mn0);
    float p02 = __expf(s02 - mn0), p03 = __expf(s03 - mn0);
    float p10 = __expf(s10 - mn1), p11 = __expf(s11 - mn1);
    float p12 = __expf(s12 - mn1), p13 = __expf(s13 - mn1);
    float ls0 = p00 + p01 + p02 + p03;
    float ls1 = p10 + p11 + p12 + p13;
#pragma unroll
    for (int mm = 1; mm <= 8; mm <<= 1) {
      ls0 += __shfl_xor(ls0, mm, 64);
      ls1 += __shfl_xor(ls1, mm, 64);
    }
    l0 = l0 * sc0 + ls0;
    l1 = l1 * sc1 + ls1;
    o0.x *= sc0; o0.y *= sc0; o0.z *= sc0; o0.w *= sc0;
    o1.x *= sc1; o1.y *= sc1; o1.z *= sc1; o1.w *= sc1;
    m0 = mn0; m1 = mn1;

    *reinterpret_cast<float4*>(&sP[2 * qp + 0][kg * 4]) = make_float4(p00, p01, p02, p03);
    *reinterpret_cast<float4*>(&sP[2 * qp + 1][kg * 4]) = make_float4(p10, p11, p12, p13);
    __syncthreads();  // scores done reading sKV(K); sP visible

    // stage V (row layout) into sKV, overwriting K
    {
      const float4* Vg4 = reinterpret_cast<const float4*>(Vb + (size_t)k0 * DHEAD);
      for (int it = 0; it < 4; ++it) {
        int f = tid + it * 256;
        int row = f >> 4, c4 = f & 15;
        *reinterpret_cast<float4*>(&sKV[row][c4 * 4]) = Vg4[f];
      }
    }
    __syncthreads();  // V ready

    // ---- PV: rows {2qp,2qp+1} x dims {4kg..4kg+3}, over 64 keys ----
#pragma unroll
    for (int k4 = 0; k4 < 16; ++k4) {
      float4 pa = *reinterpret_cast<const float4*>(&sP[2 * qp + 0][k4 * 4]);
      float4 pb = *reinterpret_cast<const float4*>(&sP[2 * qp + 1][k4 * 4]);
#pragma unroll
      for (int e = 0; e < 4; ++e) {
        float4 vv = *reinterpret_cast<const float4*>(&sKV[k4 * 4 + e][kg * 4]);
        float w0 = (e == 0) ? pa.x : (e == 1) ? pa.y : (e == 2) ? pa.z : pa.w;
        float w1 = (e == 0) ? pb.x : (e == 1) ? pb.y : (e == 2) ? pb.z : pb.w;
        o0.x += w0 * vv.x; o0.y += w0 * vv.y; o0.z += w0 * vv.z; o0.w += w0 * vv.w;
        o1.x += w1 * vv.x; o1.y += w1 * vv.y; o1.z += w1 * vv.z; o1.w += w1 * vv.w;
      }
    }
  }

  *reinterpret_cast<float4*>(slot + (2 * qp + 0) * 64 + kg * 4) = o0;
  *reinterpret_cast<float4*>(slot + (2 * qp + 1) * 64 + kg * 4) = o1;
  if (kg == 0) {
    slot[2048 + 2 * qp + 0] = m0;
    slot[2048 + 2 * qp + 1] = m1;
    slot[2080 + 2 * qp + 0] = l0;
    slot[2080 + 2 * qp + 1] = l1;
  }
}

// ---------------- split-K attention: combine ----------------
__global__ __launch_bounds__(256) void attention_combine_kernel(
    const float* __restrict__ part, float* __restrict__ attn_out) {
  const int bid = blockIdx.x;  // 512 = h*32 + qt
  const int h = bid >> 5, qt = bid & 31;
  const int g = qt >> 3;
  const int sbase = qt + 4 * g * (g - 1) + (qt - 8 * g) * g;
  const int nc = g + 1;
  const float* P0 = part + ((size_t)h * 80 + sbase) * 2112;
  const int tid = threadIdx.x;
  const int r = tid >> 3, dg = tid & 7;

  float mstar = -3.0e38f;
  for (int c2 = 0; c2 < nc; ++c2) mstar = fmaxf(mstar, P0[c2 * 2112 + 2048 + r]);
  float a0 = 0, a1 = 0, a2 = 0, a3 = 0, a4 = 0, a5 = 0, a6 = 0, a7 = 0;
  float lsum = 0.f;
  for (int c2 = 0; c2 < nc; ++c2) {
    const float* S = P0 + c2 * 2112;
    float f = __expf(S[2048 + r] - mstar);
    lsum += S[2080 + r] * f;
    const float4* o4 = reinterpret_cast<const float4*>(S + r * 64 + dg * 8);
    float4 u = o4[0], v = o4[1];
    a0 += u.x * f; a1 += u.y * f; a2 += u.z * f; a3 += u.w * f;
    a4 += v.x * f; a5 += v.y * f; a6 += v.z * f; a7 += v.w * f;
  }
  const float inv = 1.f / lsum;
  float* dst = attn_out + (size_t)(qt * 32 + r) * DMODEL + h * DHEAD + dg * 8;
  *reinterpret_cast<float4*>(dst) = make_float4(a0 * inv, a1 * inv, a2 * inv, a3 * inv);
  *reinterpret_cast<float4*>(dst + 4) = make_float4(a4 * inv, a5 * inv, a6 * inv, a7 * inv);
}

// ---------------- fallback single-pass attention (small ws) ----------------
__global__ __launch_bounds__(256) void attention_kernel(
    const float* __restrict__ Q, const float* __restrict__ K,
    const float* __restrict__ V, float* __restrict__ attn_out) {
  __shared__ float sQ[32][68];
  __shared__ float sKT[64][68];
  __shared__ float sV[64][68];
  __shared__ float sP[32][68];

  const int tid = threadIdx.x;
  const int bid = blockIdx.x;
  const int xcd = bid & 7;
  const int slot = bid >> 3;
  const int h = xcd + 8 * (slot >> 5);
  const int w = slot & 31;
  const int phase = w >> 4;
  const int j0 = w & 15;
  const int qt = phase ? (31 - j0) : j0;
  const int q0 = qt * 32;
  const int ntiles = (qt + 2) >> 1;

  const int qp = tid >> 4;
  const int kg = tid & 15;

  const float* Qb = Q + (size_t)h * S_TOK * DHEAD;
  const float* Kb = K + (size_t)h * S_TOK * DHEAD;
  const float* Vb = V + (size_t)h * S_TOK * DHEAD;

  {
    const float4* Qg4 = reinterpret_cast<const float4*>(Qb + (size_t)q0 * DHEAD);
    for (int f = tid; f < 512; f += 256) {
      float4 v = Qg4[f];
      int row = f >> 4, c4 = f & 15;
      float* dst = &sQ[row][c4 * 4];
      dst[0] = v.x * 0.125f; dst[1] = v.y * 0.125f;
      dst[2] = v.z * 0.125f; dst[3] = v.w * 0.125f;
    }
  }

  float m0 = -3.0e38f, m1 = -3.0e38f, l0 = 0.f, l1 = 0.f;
  float4 o0 = make_float4(0.f, 0.f, 0.f, 0.f);
  float4 o1 = make_float4(0.f, 0.f, 0.f, 0.f);

  const int qg0 = q0 + 2 * qp, qg1 = qg0 + 1;

  for (int t = 0; t < ntiles; ++t) {
    const int k0 = t * 64;
    __syncthreads();
    {
      const float4* Kg4 = reinterpret_cast<const float4*>(Kb + (size_t)k0 * DHEAD);
      for (int it = 0; it < 4; ++it) {
        int f = tid + it * 256;
        int row = f & 63;
        int c4 = f >> 6;
        float4 v = Kg4[row * 16 + c4];
        sKT[c4 * 4 + 0][row] = v.x; sKT[c4 * 4 + 1][row] = v.y;
        sKT[c4 * 4 + 2][row] = v.z; sKT[c4 * 4 + 3][row] = v.w;
      }
      const float4* Vg4 = reinterpret_cast<const float4*>(Vb + (size_t)k0 * DHEAD);
      for (int it = 0; it < 4; ++it) {
        int f = tid + it * 256;
        int row = f >> 4, c4 = f & 15;
        *reinterpret_cast<float4*>(&sV[row][c4 * 4]) = Vg4[f];
      }
    }
    __syncthreads();

    float s00 = 0, s01 = 0, s02 = 0, s03 = 0;
    float s10 = 0, s11 = 0, s12 = 0, s13 = 0;
#pragma unroll
    for (int d4 = 0; d4 < 16; ++d4) {
      float4 qv0 = *reinterpret_cast<const float4*>(&sQ[2 * qp + 0][d4 * 4]);
      float4 qv1 = *reinterpret_cast<const float4*>(&sQ[2 * qp + 1][d4 * 4]);
#pragma unroll
      for (int e = 0; e < 4; ++e) {
        float4 kv = *reinterpret_cast<const float4*>(&sKT[d4 * 4 + e][kg * 4]);
        float qa = (e == 0) ? qv0.x : (e == 1) ? qv0.y : (e == 2) ? qv0.z : qv0.w;
        float qb = (e == 0) ? qv1.x : (e == 1) ? qv1.y : (e == 2) ? qv1.z : qv1.w;
        s00 += qa * kv.x; s01 += qa * kv.y; s02 += qa * kv.z; s03 += qa * kv.w;
        s10 += qb * kv.x; s11 += qb * kv.y; s12 += qb * kv.z; s13 += qb * kv.w;
      }
    }
    const int kb = k0 + kg * 4;
    if (kb + 0 > qg0) s00 = -3.0e38f;
    if (kb + 1 > qg0) s01 = -3.0e38f;
    if (kb + 2 > qg0) s02 = -3.0e38f;
    if (kb + 3 > qg0) s03 = -3.0e38f;
    if (kb + 0 > qg1) s10 = -3.0e38f;
    if (kb + 1 > qg1) s11 = -3.0e38f;
    if (kb + 2 > qg1) s12 = -3.0e38f;
    if (kb + 3 > qg1) s13 = -3.0e38f;

    float lm0 = fmaxf(fmaxf(s00, s01), fmaxf(s02, s03));
    float lm1 = fmaxf(fmaxf(s10, s11), fmaxf(s12, s13));
#pragma unroll
    for (int mm = 1; mm <= 8; mm <<= 1) {
      lm0 = fmaxf(lm0, __shfl_xor(lm0, mm, 64));
      lm1 = fmaxf(lm1, __shfl_xor(lm1, mm, 64));
    }
    float mn0 = fmaxf(m0, lm0), mn1 = fmaxf(m1, lm1);
    float sc0 = expf(m0 - mn0), sc1 = expf(m1 - mn1);
    float p00 = expf(s00 - mn0), p01 = expf(s01 - mn0);
    float p02 = expf(s02 - mn0), p03 = expf(s03 - mn0);
    float p10 = expf(s10 - mn1), p11 = expf(s11 - mn1);
    float p12 = expf(s12 - mn1), p13 = expf(s13 - mn1);
    float ls0 = p00 + p01 + p02 + p03;
    float ls1 = p10 + p11 + p12 + p13;
#pragma unroll
    for (int mm = 1; mm <= 8; mm <<= 1) {
      ls0 += __shfl_xor(ls0, mm, 64);
      ls1 += __shfl_xor(ls1, mm, 64);
    }
    l0 = l0 * sc0 + ls0;
    l1 = l1 * sc1 + ls1;
    o0.x *= sc0; o0.y *= sc0; o0.z *= sc0; o0.w *= sc0;
    o1.x *= sc1; o1.y *= sc1; o1.z *= sc1; o1.w *= sc1;
    m0 = mn0; m1 = mn1;

    *reinterpret_cast<float4*>(&sP[2 * qp + 0][kg * 4]) = make_float4(p00, p01, p02, p03);
    *reinterpret_cast<float4*>(&sP[2 * qp + 1][kg * 4]) = make_float4(p10, p11, p12, p13);
    __syncthreads();

#pragma unroll
    for (int k4 = 0; k4 < 16; ++k4) {
      float4 pa = *reinterpret_cast<const float4*>(&sP[2 * qp + 0][k4 * 4]);
      float4 pb = *reinterpret_cast<const float4*>(&sP[2 * qp + 1][k4 * 4]);
#pragma unroll
      for (int e = 0; e < 4; ++e) {
        float4 vv = *reinterpret_cast<const float4*>(&sV[k4 * 4 + e][kg * 4]);
        float w0 = (e == 0) ? pa.x : (e == 1) ? pa.y : (e == 2) ? pa.z : pa.w;
        float w1 = (e == 0) ? pb.x : (e == 1) ? pb.y : (e == 2) ? pb.z : pb.w;
        o0.x += w0 * vv.x; o0.y += w0 * vv.y; o0.z += w0 * vv.z; o0.w += w0 * vv.w;
        o1.x += w1 * vv.x; o1.y += w1 * vv.y; o1.z += w1 * vv.z; o1.w += w1 * vv.w;
      }
    }
  }

  const float inv0 = 1.f / l0, inv1 = 1.f / l1;
  float4 r0 = make_float4(o0.x * inv0, o0.y * inv0, o0.z * inv0, o0.w * inv0);
  float4 r1 = make_float4(o1.x * inv1, o1.y * inv1, o1.z * inv1, o1.w * inv1);
  *reinterpret_cast<float4*>(attn_out + (size_t)qg0 * DMODEL + h * DHEAD + kg * 4) = r0;
  *reinterpret_cast<float4*>(attn_out + (size_t)qg1 * DMODEL + h * DHEAD + kg * 4) = r1;
}

// ---------------- split-K projection: partial ----------------
__global__ __launch_bounds__(256) void proj_partial_kernel(
    const float* __restrict__ A, const float* __restrict__ Bm,
    float* __restrict__ part) {
  __shared__ float sA[64][68];
  __shared__ float sB[64][68];
  const int tid = threadIdx.x;
  const int tr = tid >> 4, tc = tid & 15;
  const int col0 = blockIdx.x * 64, row0 = blockIdx.y * 64;
  const int z = blockIdx.z;
  const int kbase = z * 256;
  float acc[4][4];
#pragma unroll
  for (int i = 0; i < 4; ++i)
#pragma unroll
    for (int j = 0; j < 4; ++j) acc[i][j] = 0.f;

  for (int kt = 0; kt < 4; ++kt) {
    const int k0 = kbase + kt * 64;
    __syncthreads();
    {
      const float4* Ag = reinterpret_cast<const float4*>(A + (size_t)row0 * DMODEL + k0);
#pragma unroll
      for (int it = 0; it < 4; ++it) {
        int f = tid + it * 256;
        int r = f >> 4, c4 = f & 15;
        *reinterpret_cast<float4*>(&sA[r][c4 * 4]) = Ag[r * 256 + c4];
      }
      const float4* Bg = reinterpret_cast<const float4*>(Bm + (size_t)k0 * DMODEL + col0);
#pragma unroll
      for (int it = 0; it < 4; ++it) {
        int f = tid + it * 256;
        int r = f >> 4, c4 = f & 15;
        *reinterpret_cast<float4*>(&sB[r][c4 * 4]) = Bg[r * 256 + c4];
      }
    }
    __syncthreads();
#pragma unroll 4
    for (int kk = 0; kk < 64; ++kk) {
      float a0 = sA[tr * 4 + 0][kk], a1 = sA[tr * 4 + 1][kk];
      float a2 = sA[tr * 4 + 2][kk], a3 = sA[tr * 4 + 3][kk];
      float4 b = *reinterpret_cast<const float4*>(&sB[kk][tc * 4]);
      acc[0][0] += a0 * b.x; acc[0][1] += a0 * b.y; acc[0][2] += a0 * b.z; acc[0][3] += a0 * b.w;
      acc[1][0] += a1 * b.x; acc[1][1] += a1 * b.y; acc[1][2] += a1 * b.z; acc[1][3] += a1 * b.w;
      acc[2][0] += a2 * b.x; acc[2][1] += a2 * b.y; acc[2][2] += a2 * b.z; acc[2][3] += a2 * b.w;
      acc[3][0] += a3 * b.x; acc[3][1] += a3 * b.y; acc[3][2] += a3 * b.z; acc[3][3] += a3 * b.w;
    }
  }

  float* dst = part + (size_t)z * (DMODEL * S_TOK);
#pragma unroll
  for (int i = 0; i < 4; ++i) {
    *reinterpret_cast<float4*>(dst + (size_t)(row0 + tr * 4 + i) * DMODEL + col0 + tc * 4) =
        make_float4(acc[i][0], acc[i][1], acc[i][2], acc[i][3]);
  }
}

// ---------------- projection combine: H = x + sum_z part[z] ----------------
__global__ __launch_bounds__(256) void proj_combine_kernel(
    const float* __restrict__ part, const float* __restrict__ x,
    float* __restrict__ H) {
  const int i = blockIdx.x * 256 + threadIdx.x;
  const float4* p4 = reinterpret_cast<const float4*>(part);
  float4 p0 = p4[i];
  float4 p1 = p4[i + 262144];
  float4 p2 = p4[i + 524288];
  float4 p3 = p4[i + 786432];
  float4 xv = reinterpret_cast<const float4*>(x)[i];
  reinterpret_cast<float4*>(H)[i] =
      make_float4(xv.x + p0.x + p1.x + p2.x + p3.x, xv.y + p0.y + p1.y + p2.y + p3.y,
                  xv.z + p0.z + p1.z + p2.z + p3.z, xv.w + p0.w + p1.w + p2.w + p3.w);
}

// ---------------- fallback proj (small ws) ----------------
__global__ __launch_bounds__(256) void proj_add_kernel(
    const float* __restrict__ A, const float* __restrict__ Bm,
    const float* __restrict__ x, float* __restrict__ H) {
  __shared__ float sA[64][65];
  __shared__ float sB[64][65];
  const int tid = threadIdx.x;
  const int tr = tid >> 4, tc = tid & 15;
  const int row0 = blockIdx.y * 64, col0 = blockIdx.x * 64;
  float acc[4][4];
#pragma unroll
  for (int i = 0; i < 4; ++i)
#pragma unroll
    for (int j = 0; j < 4; ++j) acc[i][j] = 0.f;
  for (int kt = 0; kt < 16; ++kt) {
#pragma unroll
    for (int e = tid; e < 4096; e += 256) {
      int r = e >> 6, c = e & 63;
      sA[r][c] = A[(size_t)(row0 + r) * DMODEL + (kt * 64 + c)];
      sB[r][c] = Bm[(size_t)(kt * 64 + r) * DMODEL + (col0 + c)];
    }
    __syncthreads();
#pragma unroll 4
    for (int kk = 0; kk < 64; ++kk) {
      float a0 = sA[tr * 4 + 0][kk], a1 = sA[tr * 4 + 1][kk];
      float a2 = sA[tr * 4 + 2][kk], a3 = sA[tr * 4 + 3][kk];
      float b0 = sB[kk][tc * 4 + 0], b1 = sB[kk][tc * 4 + 1];
      float b2 = sB[kk][tc * 4 + 2], b3 = sB[kk][tc * 4 + 3];
      acc[0][0] += a0 * b0; acc[0][1] += a0 * b1; acc[0][2] += a0 * b2; acc[0][3] += a0 * b3;
      acc[1][0] += a1 * b0; acc[1][1] += a1 * b1; acc[1][2] += a1 * b2; acc[1][3] += a1 * b3;
      acc[2][0] += a2 * b0; acc[2][1] += a2 * b1; acc[2][2] += a2 * b2; acc[2][3] += a2 * b3;
      acc[3][0] += a3 * b0; acc[3][1] += a3 * b1; acc[3][2] += a3 * b2; acc[3][3] += a3 * b3;
    }
    __syncthreads();
  }
#pragma unroll
  for (int i = 0; i < 4; ++i) {
    size_t ro = (size_t)(row0 + tr * 4 + i) * DMODEL + col0 + tc * 4;
#pragma unroll
    for (int j = 0; j < 4; ++j) H[ro + j] = x[ro + j] + acc[i][j];
  }
}

// ---------------- know token kernel (pass-2 over gate survivors only) ----------------
__global__ __launch_bounds__(256) void know_token_kernel(
    const float* __restrict__ h, const float* __restrict__ tau,
    const float* __restrict__ know_neurons,
    const int* __restrict__ idxk, const float* __restrict__ dk,
    float* __restrict__ out, float* __restrict__ loss_acc) {
  const int s = blockIdx.x;
  const int tid = threadIdx.x;
  const int lane = tid & 63, wave = tid >> 6;
  __shared__ __align__(16) float s_h[DMODEL];
  __shared__ float s_act[128];
  __shared__ float s_eg[128];
  __shared__ float s_w[128];
  __shared__ float s_wg[128];
  __shared__ float s_g[128];
  __shared__ int s_idx[128];
  __shared__ int s_klist[128];
  __shared__ int s_wcnt[2];
  __shared__ int s_kcnt;
  __shared__ float s_kth, s_gsum, s_strength;

  for (int i = tid; i < DMODEL; i += 256) s_h[i] = h[(size_t)s * DMODEL + i];
  if (tid < 128) s_idx[tid] = idxk[s * 128 + tid];
  __syncthreads();

  const float4* h4 = reinterpret_cast<const float4*>(s_h);
  for (int c = wave * 32; c < wave * 32 + 32; ++c) {
    const float4* row4 = reinterpret_cast<const float4*>(know_neurons + (size_t)s_idx[c] * DMODEL);
    float acc = 0.f;
#pragma unroll
    for (int k = 0; k < 4; ++k) {
      float4 rv = row4[lane + k * 64];
      float4 xv = h4[lane + k * 64];
      acc += rv.x * xv.x + rv.y * xv.y + rv.z * xv.z + rv.w * xv.w;
    }
    acc = wave_reduce_sum(acc);
    if (lane == 0) s_act[c] = acc;
  }
  __syncthreads();

  const float tv = tau[s];
  if (tid < 128) {
    float a = s_act[tid];
    float raw = a - tv;
    float gate = (raw > 0.f) ? raw : 1e-8f * __expf(raw);
    s_eg[tid] = __expf(gate) - 1.f;
  }
  __syncthreads();
  if (tid < 128) {
    float e = s_eg[tid];
    int rank = 0;
    for (int j = 0; j < 128; ++j) {
      float ej = s_eg[j];
      rank += ((ej > e) || (ej == e && j < tid)) ? 1 : 0;
    }
    if (rank == 63) s_kth = e;
  }
  __syncthreads();
  if (tid < 128) {
    float e = s_eg[tid];
    s_w[tid] = (e >= s_kth) ? e : 0.f;
  }
  __syncthreads();
  if (wave == 0) {
    float sum = wave_reduce_sum(s_w[lane] + s_w[lane + 64]);
    float mx = wave_reduce_max(fmaxf(s_eg[lane], s_eg[lane + 64]));
    if (lane == 0) { s_gsum = sum + 1e-8f; s_strength = tanhf(mx); }
  }
  // survivor compaction phase 1: per-wave counts
  if (tid < 128) {
    bool pred = s_w[tid] != 0.f;
    unsigned long long m = __ballot(pred);
    if (lane == 0) s_wcnt[wave] = __popcll(m);
  }
  __syncthreads();
  if (tid < 128) {
    float g = s_w[tid] / s_gsum * s_strength;
    s_g[tid] = g;
    s_wg[tid] = s_act[tid] * g;
    bool pred = s_w[tid] != 0.f;
    unsigned long long m = __ballot(pred);
    int base = (wave == 1) ? s_wcnt[0] : 0;
    int pos = base + __popcll(m & ((1ull << lane) - 1ull));
    if (pred) s_klist[pos] = tid;
    if (tid == 0) s_kcnt = s_wcnt[0] + s_wcnt[1];
  }
  __syncthreads();
  if (wave == 0) {
    float pl = s_g[lane] * dk[s * 128 + lane] + s_g[lane + 64] * dk[s * 128 + lane + 64];
    pl = wave_reduce_sum(pl);
    if (lane == 0) atomicAdd(loss_acc, pl * (1.f / 131072.f));
  }

  const int d0 = tid * 4;
  const int kc = s_kcnt;
  float a0 = 0, a1 = 0, a2 = 0, a3 = 0;
  for (int j = 0; j < kc; ++j) {
    const int c = s_klist[j];
    const float4 r = *reinterpret_cast<const float4*>(know_neurons + (size_t)s_idx[c] * DMODEL + d0);
    const float wv = s_wg[c];
    a0 += wv * r.x; a1 += wv * r.y; a2 += wv * r.z; a3 += wv * r.w;
  }
  float h0 = s_h[d0 + 0], h1 = s_h[d0 + 1], h2 = s_h[d0 + 2], h3 = s_h[d0 + 3];
  *reinterpret_cast<float4*>(out + (size_t)s * DMODEL + d0) =
      make_float4(h0 + a0, h1 + a1, h2 + a2, h3 + a3);
}

extern "C" void kernel_launch(void* const* d_in, const int* in_sizes, int n_in,
                              void* d_out, int out_size, void* d_ws, size_t ws_size,
                              hipStream_t stream) {
  const float* x = (const float*)d_in[0];
  const float* qk_pos = (const float*)d_in[1];
  const float* v_pos = (const float*)d_in[2];
  const float* know_pos = (const float*)d_in[3];
  const float* tau_q = (const float*)d_in[4];
  const float* tau_k = (const float*)d_in[5];
  const float* tau_v = (const float*)d_in[6];
  const float* tau_know = (const float*)d_in[7];
  const float* qk_neurons = (const float*)d_in[8];
  const float* v_neurons = (const float*)d_in[9];
  const float* know_neurons = (const float*)d_in[10];
  const float* npos_qk = (const float*)d_in[11];
  const float* npos_v = (const float*)d_in[12];
  const float* npos_know = (const float*)d_in[13];
  const float* expand_O = (const float*)d_in[14];
  float* out = (float*)d_out;
  float* loss_acc = out + (size_t)S_TOK * DMODEL;

  char* w = (char*)d_ws;
  int* idx_qk = (int*)(w + 0);
  float* dist_qk = (float*)(w + 262144);
  int* idx_v = (int*)(w + 524288);
  float* dist_v = (float*)(w + 786432);
  int* idx_know = (int*)(w + 1048576);
  float* dist_know = (float*)(w + 1572864);
  float* Qb = (float*)(w + 2097152);
  float* Kb = (float*)(w + 6291456);
  float* Vb = (float*)(w + 10485760);
  float* attnbuf = (float*)(w + 14680064);
  float* hbuf = (float*)(w + 18874368);
  float* Rbuf = (float*)(w + 23068672);  // 16 MB scratch: selects -> attn partials -> proj partials

  hipMemsetAsync(loss_acc, 0, sizeof(float), stream);

  const bool big_ws = ws_size >= (size_t)23068672 + 16777216;
  if (big_ws) {
    rgemm_kernel<<<dim3(32, 16), 256, 0, stream>>>(qk_pos, npos_qk, Rbuf, 0, 4096);
    select2_kernel<4096, 64><<<1024, 256, 0, stream>>>(Rbuf, qk_pos, npos_qk, 0, idx_qk, dist_qk);
    rgemm_kernel<<<dim3(32, 16), 256, 0, stream>>>(v_pos, npos_v, Rbuf, 0, 4096);
    select2_kernel<4096, 64><<<1024, 256, 0, stream>>>(Rbuf, v_pos, npos_v, 0, idx_v, dist_v);
    rgemm_kernel<<<dim3(64, 8), 256, 0, stream>>>(know_pos, npos_know, Rbuf, 0, 8192);
    select2_kernel<8192, 128><<<512, 256, 0, stream>>>(Rbuf, know_pos, npos_know, 0, idx_know, dist_know);
    rgemm_kernel<<<dim3(64, 8), 256, 0, stream>>>(know_pos, npos_know, Rbuf, 512, 8192);
    select2_kernel<8192, 128><<<512, 256, 0, stream>>>(Rbuf, know_pos, npos_know, 512, idx_know, dist_know);
  } else {
    select_topk_fused_kernel<4096, 64><<<S_TOK, 256, 0, stream>>>(qk_pos, npos_qk, idx_qk, dist_qk);
    select_topk_fused_kernel<4096, 64><<<S_TOK, 256, 0, stream>>>(v_pos, npos_v, idx_v, dist_v);
    select_topk_fused_kernel<8192, 128><<<S_TOK, 256, 0, stream>>>(know_pos, npos_know, idx_know, dist_know);
  }

  attn_token_kernel<<<S_TOK, 256, 0, stream>>>(x, tau_q, tau_k, tau_v, qk_neurons, v_neurons,
                                               idx_qk, dist_qk, idx_v, dist_v, Qb, Kb, Vb, loss_acc);

  if (big_ws) {
    attention_partial_kernel<<<1280, 256, 0, stream>>>(Qb, Kb, Vb, Rbuf);
    attention_combine_kernel<<<512, 256, 0, stream>>>(Rbuf, attnbuf);
    proj_partial_kernel<<<dim3(16, 16, 4), 256, 0, stream>>>(attnbuf, expand_O, Rbuf);
    proj_combine_kernel<<<1024, 256, 0, stream>>>(Rbuf, x, hbuf);
  } else {
    attention_kernel<<<512, 256, 0, stream>>>(Qb, Kb, Vb, attnbuf);
    proj_add_kernel<<<dim3(16, 16), 256, 0, stream>>>(attnbuf, expand_O, x, hbuf);
  }

  know_token_kernel<<<S_TOK, 256, 0, stream>>>(hbuf, tau_know, know_neurons, idx_know, dist_know,
                                               out, loss_acc);
}